// Round 13
// baseline (220.517 us; speedup 1.0000x reference)
//
#include <hip/hip_runtime.h>

typedef __bf16 bf16;
typedef __attribute__((ext_vector_type(2))) __bf16 bf16x2;
typedef __attribute__((ext_vector_type(4))) __bf16 bf16x4;
typedef __attribute__((ext_vector_type(8))) __bf16 bf16x8;
typedef __attribute__((ext_vector_type(4))) float f32x4;
typedef __attribute__((ext_vector_type(16))) float f32x16;

#define B_ 4
#define S_ 2048
#define H_ 16
#define D_ 64
#define E_ 1024

#define BM 256
#define BN 128
#define BK 64

__device__ __forceinline__ int imin(int a, int b) { return a < b ? a : b; }
__device__ __forceinline__ int imax(int a, int b) { return a > b ? a : b; }

__device__ __forceinline__ void gload_lds16(const void* g, void* l) {
  __builtin_amdgcn_global_load_lds(
      (const __attribute__((address_space(1))) void*)g,
      (__attribute__((address_space(3))) void*)l, 16, 0, 0);
}

// ------ fused f32 -> bf16 convert for x (4096 blk), Wqkv (1536), Wout (512) --
__global__ __launch_bounds__(256) void cvt3_kernel(
    const float* __restrict__ x, bf16* __restrict__ xb,
    const float* __restrict__ wqkv, bf16* __restrict__ wqkvb,
    const float* __restrict__ wout, bf16* __restrict__ woutb) {
  const int bid = blockIdx.x;
  const float* in;
  bf16* out;
  int idx;
  if (bid < 4096) { in = x; out = xb; idx = bid; }
  else if (bid < 5632) { in = wqkv; out = wqkvb; idx = bid - 4096; }
  else { in = wout; out = woutb; idx = bid - 5632; }
  const int i = (idx * 256 + threadIdx.x) * 8;
  float4 v0 = *(const float4*)(in + i);
  float4 v1 = *(const float4*)(in + i + 4);
  bf16x8 o;
  o[0] = (bf16)v0.x; o[1] = (bf16)v0.y; o[2] = (bf16)v0.z; o[3] = (bf16)v0.w;
  o[4] = (bf16)v1.x; o[5] = (bf16)v1.y; o[6] = (bf16)v1.z; o[7] = (bf16)v1.w;
  *(bf16x8*)(out + i) = o;
}

// ------------- NT bf16 GEMM, 256x128 tile, 3-buf distance-2 pipeline -------
// Round-8 version restored verbatim (best measured: 75.2 us, conflicts = 0).
__global__ __launch_bounds__(512, 1) void gemm_pipe(
    const bf16* __restrict__ A, const bf16* __restrict__ Bm,
    int M, int N, int K, int mode,
    bf16* __restrict__ qd, bf16* __restrict__ kd, bf16* __restrict__ vtd,
    float* __restrict__ outf) {
  __shared__ __align__(16) bf16 As[3][BM * BK];
  __shared__ __align__(16) bf16 Bs[3][BN * BK];
  const int tid = threadIdx.x;
  const int wave = tid >> 6, lane = tid & 63;
  const int l15 = lane & 15, l4 = lane >> 4;
  const int wm = (wave >> 1) * 64;
  const int wn = (wave & 1) * 64;

  const int nwg = gridDim.x * gridDim.y;
  const int fid = blockIdx.y * gridDim.x + blockIdx.x;
  const int chunk = nwg >> 3;
  const int swz = (fid & 7) * chunk + (fid >> 3);
  const int tn = swz % gridDim.x;
  const int tm = swz / gridDim.x;

  const bf16* Abase = A + (size_t)tm * BM * K;
  const bf16* Bbase = Bm + (size_t)tn * BN * K;

  f32x4 acc[4][4];
#pragma unroll
  for (int i = 0; i < 4; ++i)
#pragma unroll
    for (int j = 0; j < 4; ++j)
#pragma unroll
      for (int r = 0; r < 4; ++r) acc[i][j][r] = 0.f;

  const int NT = K >> 6;

#define STAGE_A(sbuf, k0)                                                      \
  {                                                                            \
    _Pragma("unroll") for (int ld = 0; ld < 4; ++ld) {                         \
      const int idx = ld * 512 + tid;                                          \
      const int row = idx >> 3, g = idx & 7;                                   \
      const int gs = g ^ (row & 7);                                            \
      gload_lds16(Abase + (size_t)row * K + (k0) + gs * 8,                     \
                  As[sbuf] + (ld * 512 + wave * 64) * 8);                      \
    }                                                                          \
  }
#define STAGE_B(sbuf, k0)                                                      \
  {                                                                            \
    _Pragma("unroll") for (int ld = 0; ld < 2; ++ld) {                         \
      const int idx = ld * 512 + tid;                                          \
      const int row = idx >> 3, g = idx & 7;                                   \
      const int gs = g ^ (row & 7);                                            \
      gload_lds16(Bbase + (size_t)row * K + (k0) + gs * 8,                     \
                  Bs[sbuf] + (ld * 512 + wave * 64) * 8);                      \
    }                                                                          \
  }

  STAGE_A(0, 0); STAGE_B(0, 0);
  STAGE_A(1, BK); STAGE_B(1, BK);
  asm volatile("s_waitcnt vmcnt(6)" ::: "memory");
  __builtin_amdgcn_s_barrier();

  int p = 0;
  for (int t = 0; t < NT; ++t) {
    const bf16* Ap = As[p];
    const bf16* Bp = Bs[p];
    const int sb = (p + 2 >= 3) ? p - 1 : p + 2;
    const int sk0 = ((t + 2 < NT) ? t + 2 : NT - 1) * BK;

    bf16x8 a[4], bfr[4];
#pragma unroll
    for (int i = 0; i < 4; ++i) {
      const int ra = wm + i * 16 + l15;
      a[i] = *(const bf16x8*)(Ap + ra * 64 + ((l4 ^ (ra & 7)) * 8));
      const int rb = wn + i * 16 + l15;
      bfr[i] = *(const bf16x8*)(Bp + rb * 64 + ((l4 ^ (rb & 7)) * 8));
    }
    STAGE_A(sb, sk0);
    __builtin_amdgcn_s_setprio(1);
#pragma unroll
    for (int i = 0; i < 4; ++i)
#pragma unroll
      for (int j = 0; j < 4; ++j)
        acc[i][j] = __builtin_amdgcn_mfma_f32_16x16x32_bf16(a[i], bfr[j],
                                                            acc[i][j], 0, 0, 0);
    __builtin_amdgcn_s_setprio(0);
#pragma unroll
    for (int i = 0; i < 4; ++i) {
      const int ra = wm + i * 16 + l15;
      a[i] = *(const bf16x8*)(Ap + ra * 64 + (((4 + l4) ^ (ra & 7)) * 8));
      const int rb = wn + i * 16 + l15;
      bfr[i] = *(const bf16x8*)(Bp + rb * 64 + (((4 + l4) ^ (rb & 7)) * 8));
    }
    STAGE_B(sb, sk0);
    __builtin_amdgcn_s_setprio(1);
#pragma unroll
    for (int i = 0; i < 4; ++i)
#pragma unroll
      for (int j = 0; j < 4; ++j)
        acc[i][j] = __builtin_amdgcn_mfma_f32_16x16x32_bf16(a[i], bfr[j],
                                                            acc[i][j], 0, 0, 0);
    __builtin_amdgcn_s_setprio(0);

    asm volatile("s_waitcnt vmcnt(6)" ::: "memory");
    __builtin_amdgcn_s_barrier();
    p = (p + 1 >= 3) ? 0 : p + 1;
  }
#undef STAGE_A
#undef STAGE_B

  if (mode == 0) {
#pragma unroll
    for (int i = 0; i < 4; ++i) {
      const int m0 = tm * BM + wm + i * 16 + l4 * 4;
      const int b = m0 >> 11, s = m0 & (S_ - 1);
#pragma unroll
      for (int j = 0; j < 4; ++j) {
        const int n = tn * BN + wn + j * 16 + l15;
        const int which = n >> 10;
        const int hn = n & 1023;
        const int h = hn >> 6, d = hn & 63;
        const f32x4 av = acc[i][j];
        if (which == 0) {
#pragma unroll
          for (int r = 0; r < 4; ++r)
            qd[((size_t)(b * H_ + h) * S_ + (s + r)) * D_ + d] =
                (bf16)(av[r] * 0.125f);
        } else if (which == 1) {
#pragma unroll
          for (int r = 0; r < 4; ++r)
            kd[((size_t)(b * H_ + h) * S_ + (s + r)) * D_ + d] = (bf16)av[r];
        } else {
          bf16x4 pv;
#pragma unroll
          for (int r = 0; r < 4; ++r) pv[r] = (bf16)av[r];
          *(bf16x4*)(vtd + ((size_t)(b * H_ + h) * D_ + d) * S_ + s) = pv;
        }
      }
    }
  } else {
#pragma unroll
    for (int i = 0; i < 4; ++i) {
      const int m0 = tm * BM + wm + i * 16 + l4 * 4;
#pragma unroll
      for (int j = 0; j < 4; ++j) {
        const int n = tn * BN + wn + j * 16 + l15;
#pragma unroll
        for (int r = 0; r < 4; ++r) outf[(size_t)(m0 + r) * N + n] = acc[i][j][r];
      }
    }
  }
}

// ------- mean of v over all S: 256 blocks = 64 bh x 4 d-quarters ----------
__global__ __launch_bounds__(256) void meanv_kernel(const bf16* __restrict__ vt,
                                                    float* __restrict__ meanv) {
  const int bh = blockIdx.x >> 2, dq = blockIdx.x & 3;
  const int tid = threadIdx.x;
  const int dl = tid >> 4;
  const int sl = tid & 15;
  const int d = dq * 16 + dl;
  const bf16* row = vt + ((size_t)bh * D_ + d) * S_;
  float s = 0.f;
#pragma unroll
  for (int it = 0; it < 16; ++it) {
    bf16x8 v = *(const bf16x8*)(row + it * 128 + sl * 8);
#pragma unroll
    for (int j = 0; j < 8; ++j) s += (float)v[j];
  }
#pragma unroll
  for (int m = 1; m < 16; m <<= 1) s += __shfl_xor(s, m, 64);
  if (sl == 0) meanv[(size_t)bh * D_ + d] = s * (1.0f / (float)S_);
}

// -------- flash attention: 4 waves x 64 q-rows (2x32 halves), KVBLK=64 LDS --
// K-tile fragments read from LDS ONCE per tile and reused for both q-halves
// (halves LDS-read bytes per q-row); same for V. Block covers 256 q-rows.
__device__ __forceinline__ int pk2(float a, float b) {
  union { bf16x2 h; int i; } u;
  u.h[0] = (bf16)a; u.h[1] = (bf16)b;
  return u.i;
}

__global__ __launch_bounds__(256) void attn_kernel(
    const bf16* __restrict__ q, const bf16* __restrict__ k,
    const bf16* __restrict__ vt, const float* __restrict__ meanv,
    const int* __restrict__ seq_lengths, const int* __restrict__ wlp,
    const int* __restrict__ wrp, bf16* __restrict__ attn_out) {
  __shared__ __align__(16) bf16 Ks[2][64 * 64];
  __shared__ __align__(16) bf16 Vs[2][64 * 64];
  const int tid = threadIdx.x, wave = tid >> 6, lane = tid & 63;
  const int l31 = lane & 31, l5 = lane >> 5;
  // XCD swizzle: 512 blocks, chunk = 64
  const int bid0 = blockIdx.x;
  const int bid = (bid0 & 7) * 64 + (bid0 >> 3);
  const int bh = bid >> 3;  // 8 blocks of 256 q-rows per (b,h)
  const int g = bid & 7;
  const int b = bh >> 4, h = bh & 15;
  const int q0b = g * 256;
  const int q0w = q0b + wave * 64;
  const int seq_len = seq_lengths[b];
  const int wl = wlp[0], wr = wrp[0];

  const bf16* qbase = q + (size_t)bh * S_ * D_;
  const bf16* kbase = k + (size_t)bh * S_ * D_;
  const bf16* vtb = vt + (size_t)bh * D_ * S_;

  // Q fragments for both halves (B-operand): col=l31=q-row
  bf16x8 qa[2][4];
#pragma unroll
  for (int h2 = 0; h2 < 2; ++h2)
#pragma unroll
    for (int dg = 0; dg < 4; ++dg)
      qa[h2][dg] = *(const bf16x8*)(qbase + (size_t)(q0w + h2 * 32 + l31) * D_ +
                                    dg * 16 + l5 * 8);

  const int hi_blk = (wr >= 0) ? imin(q0b + 255 + wr, S_ - 1) : (S_ - 1);
  const int end_blk = imin(hi_blk + 1, seq_len);
  const int lo_blk = (wl >= 0) ? imax(0, q0b - wl) : 0;
  const int beg_blk = lo_blk & ~63;
  const int ntb = (end_blk > beg_blk) ? ((end_blk - beg_blk + 63) >> 6) : 0;

  const int w_hi = (wr >= 0) ? (q0w + 63 + wr) : (S_ - 1);
  const int w_end = imin(w_hi + 1, seq_len);
  const int w_lo = (wl >= 0) ? imax(0, q0w - wl) : 0;

  f32x16 o[2][2];
#pragma unroll
  for (int h2 = 0; h2 < 2; ++h2)
#pragma unroll
    for (int dv = 0; dv < 2; ++dv)
#pragma unroll
      for (int r = 0; r < 16; ++r) o[h2][dv][r] = 0.f;
  float mrun[2] = {-1e30f, -1e30f}, lrun[2] = {0.f, 0.f};

#define STAGE(bufb, kt0)                                                       \
  {                                                                            \
    _Pragma("unroll") for (int ld = 0; ld < 2; ++ld) {                         \
      const int idx = ld * 256 + tid;                                          \
      const int row = idx >> 3, gg = idx & 7;                                  \
      const int gs = gg ^ (row & 7);                                           \
      const int krow = imin((kt0) + row, S_ - 1);                              \
      gload_lds16(kbase + (size_t)krow * 64 + gs * 8, Ks[bufb] + idx * 8);     \
      const int vcol = imin((kt0) + gs * 8, S_ - 8);                           \
      gload_lds16(vtb + (size_t)row * S_ + vcol, Vs[bufb] + idx * 8);          \
    }                                                                          \
  }
#define LDS_K(bufb, row, gran)                                                 \
  (*(const bf16x8*)((const char*)(Ks[bufb]) + (row) * 128 +                    \
                    (((gran) ^ ((row) & 7)) << 4)))
#define LDS_V(bufb, row, gran)                                                 \
  (*(const bf16x8*)((const char*)(Vs[bufb]) + (row) * 128 +                    \
                    (((gran) ^ ((row) & 7)) << 4)))

  if (ntb > 0) STAGE(0, beg_blk);
  __syncthreads();

  for (int t = 0; t < ntb; ++t) {
    const int kt = beg_blk + t * 64;
    if (t + 1 < ntb) STAGE((t + 1) & 1, kt + 64);

    const bool active = (kt < w_end) && (kt + 63 >= w_lo);
    if (active) {
      const int bufb = t & 1;
      // ---- K-tile fragments: read ONCE, reused by both q-halves ----
      bf16x8 kf0[4], kf1[4];
#pragma unroll
      for (int dg = 0; dg < 4; ++dg) {
        kf0[dg] = LDS_K(bufb, l31, dg * 2 + l5);
        kf1[dg] = LDS_K(bufb, 32 + l31, dg * 2 + l5);
      }
      // ---- QK^T both halves ----
      f32x16 sf[2][2];
#pragma unroll
      for (int h2 = 0; h2 < 2; ++h2)
#pragma unroll
        for (int kv = 0; kv < 2; ++kv)
#pragma unroll
          for (int r = 0; r < 16; ++r) sf[h2][kv][r] = 0.f;
#pragma unroll
      for (int h2 = 0; h2 < 2; ++h2)
#pragma unroll
        for (int dg = 0; dg < 4; ++dg) {
          sf[h2][0] = __builtin_amdgcn_mfma_f32_32x32x16_bf16(
              kf0[dg], qa[h2][dg], sf[h2][0], 0, 0, 0);
          sf[h2][1] = __builtin_amdgcn_mfma_f32_32x32x16_bf16(
              kf1[dg], qa[h2][dg], sf[h2][1], 0, 0, 0);
        }

      // ---- mask + softmax + pack, per half ----
      bf16x8 pb[2][4];
#pragma unroll
      for (int h2 = 0; h2 < 2; ++h2) {
        const int qlo = q0w + h2 * 32;
        bool allv = (kt + 63 < seq_len);
        if (wr >= 0) allv = allv && (kt + 63 <= qlo + wr);
        if (wl >= 0) allv = allv && (kt >= qlo + 31 - wl);
        if (!allv) {
          const int qrow = qlo + l31;
#pragma unroll
          for (int kv = 0; kv < 2; ++kv)
#pragma unroll
            for (int r = 0; r < 16; ++r) {
              const int key = kt + kv * 32 + (r & 3) + 8 * (r >> 2) + 4 * l5;
              bool valid = (key < seq_len);
              if (wr >= 0) valid = valid && (key <= qrow + wr);
              if (wl >= 0) valid = valid && (key >= qrow - wl);
              sf[h2][kv][r] = valid ? sf[h2][kv][r] : -1e30f;
            }
        }
        float tmax = -1e30f;
#pragma unroll
        for (int r = 0; r < 16; ++r) {
          tmax = fmaxf(tmax, sf[h2][0][r]);
          tmax = fmaxf(tmax, sf[h2][1][r]);
        }
        tmax = fmaxf(tmax, __shfl_xor(tmax, 32, 64));

        if (!__all(tmax <= mrun[h2] + 8.0f)) {
          const float mnew = fmaxf(mrun[h2], tmax);
          const float corr = __expf(mrun[h2] - mnew);
          mrun[h2] = mnew;
          lrun[h2] *= corr;
#pragma unroll
          for (int r = 0; r < 16; ++r) {
            o[h2][0][r] *= corr;
            o[h2][1][r] *= corr;
          }
        }

        float lsum = 0.f;
#pragma unroll
        for (int kv = 0; kv < 2; ++kv)
#pragma unroll
          for (int r = 0; r < 16; ++r) {
            const float e = (sf[h2][kv][r] <= -1e29f)
                                ? 0.f
                                : __expf(sf[h2][kv][r] - mrun[h2]);
            sf[h2][kv][r] = e;
            lsum += e;
          }
        lsum += __shfl_xor(lsum, 32, 64);
        lrun[h2] += lsum;

#pragma unroll
        for (int kg = 0; kg < 4; ++kg) {
          const int kv = kg >> 1;
          const int base = (kg & 1) * 8;
          const int w0 = pk2(sf[h2][kv][base + 0], sf[h2][kv][base + 1]);
          const int w1 = pk2(sf[h2][kv][base + 2], sf[h2][kv][base + 3]);
          const int w2 = pk2(sf[h2][kv][base + 4], sf[h2][kv][base + 5]);
          const int w3 = pk2(sf[h2][kv][base + 6], sf[h2][kv][base + 7]);
          auto r02 = __builtin_amdgcn_permlane32_swap(w0, w2, false, false);
          auto r13 = __builtin_amdgcn_permlane32_swap(w1, w3, false, false);
          union { int i[4]; bf16x8 v; } u;
          u.i[0] = r02[0]; u.i[1] = r13[0]; u.i[2] = r02[1]; u.i[3] = r13[1];
          pb[h2][kg] = u.v;
        }
      }

      // ---- V-tile fragments: read ONCE, reused by both q-halves ----
#pragma unroll
      for (int kg = 0; kg < 4; ++kg) {
        bf16x8 va0 = LDS_V(bufb, l31, kg * 2 + l5);
        bf16x8 va1 = LDS_V(bufb, 32 + l31, kg * 2 + l5);
#pragma unroll
        for (int h2 = 0; h2 < 2; ++h2) {
          o[h2][0] = __builtin_amdgcn_mfma_f32_32x32x16_bf16(va0, pb[h2][kg],
                                                             o[h2][0], 0, 0, 0);
          o[h2][1] = __builtin_amdgcn_mfma_f32_32x32x16_bf16(va1, pb[h2][kg],
                                                             o[h2][1], 0, 0, 0);
        }
      }
    }
    __syncthreads();
  }
#undef STAGE
#undef LDS_K
#undef LDS_V

  // ---- epilogue, per half ----
#pragma unroll
  for (int h2 = 0; h2 < 2; ++h2) {
    const int qrow = q0w + h2 * 32 + l31;
    bf16* outp = attn_out + ((size_t)(b * S_ + qrow)) * E_ + h * 64;
    if (lrun[h2] > 0.f) {
      const float inv = 1.0f / lrun[h2];
#pragma unroll
      for (int dv = 0; dv < 2; ++dv)
#pragma unroll
        for (int rg = 0; rg < 4; ++rg) {
          const int d0 = dv * 32 + 8 * rg + 4 * l5;
          bf16x4 ov;
#pragma unroll
          for (int j = 0; j < 4; ++j) ov[j] = (bf16)(o[h2][dv][rg * 4 + j] * inv);
          *(bf16x4*)(outp + d0) = ov;
        }
    } else {
      const float* mv = meanv + (size_t)bh * D_;
#pragma unroll
      for (int dv = 0; dv < 2; ++dv)
#pragma unroll
        for (int rg = 0; rg < 4; ++rg) {
          const int d0 = dv * 32 + 8 * rg + 4 * l5;
          bf16x4 ov;
#pragma unroll
          for (int j = 0; j < 4; ++j) ov[j] = (bf16)mv[d0 + j];
          *(bf16x4*)(outp + d0) = ov;
        }
    }
  }
}

// ---------------- launch ----------------
extern "C" void kernel_launch(void* const* d_in, const int* in_sizes, int n_in,
                              void* d_out, int out_size, void* d_ws, size_t ws_size,
                              hipStream_t stream) {
  const float* x = (const float*)d_in[0];
  const float* Wqkv = (const float*)d_in[1];
  const float* Wout = (const float*)d_in[2];
  const int* seq_lengths = (const int*)d_in[3];
  const int* wl = (const int*)d_in[4];
  const int* wr = (const int*)d_in[5];
  float* out = (float*)d_out;

  char* ws = (char*)d_ws;
  bf16* xb = (bf16*)ws;      ws += (size_t)8192 * 1024 * 2;
  bf16* wqkvb = (bf16*)ws;   ws += (size_t)3072 * 1024 * 2;
  bf16* woutb = (bf16*)ws;   ws += (size_t)1024 * 1024 * 2;
  bf16* qd = (bf16*)ws;      ws += (size_t)B_ * H_ * S_ * D_ * 2;
  bf16* kd = (bf16*)ws;      ws += (size_t)B_ * H_ * S_ * D_ * 2;
  bf16* vtd = (bf16*)ws;     ws += (size_t)B_ * H_ * S_ * D_ * 2;
  bf16* attn = (bf16*)ws;    ws += (size_t)8192 * 1024 * 2;
  float* meanv = (float*)ws; ws += (size_t)B_ * H_ * D_ * 4;

  cvt3_kernel<<<6144, 256, 0, stream>>>(x, xb, Wqkv, wqkvb, Wout, woutb);

  gemm_pipe<<<dim3(24, 32), 512, 0, stream>>>(xb, wqkvb, 8192, 3072, 1024, 0,
                                              qd, kd, vtd, nullptr);
  meanv_kernel<<<256, 256, 0, stream>>>(vtd, meanv);
  attn_kernel<<<512, 256, 0, stream>>>(qd, kd, vtd, meanv, seq_lengths, wl, wr,
                                       attn);
  gemm_pipe<<<dim3(8, 32), 512, 0, stream>>>(attn, woutb, 8192, 1024, 1024, 1,
                                             nullptr, nullptr, nullptr, out);
}

// Round 16
// 168.810 us; speedup vs baseline: 1.3063x; 1.3063x over previous
//
#include <hip/hip_runtime.h>

typedef __bf16 bf16;
typedef __attribute__((ext_vector_type(2))) __bf16 bf16x2;
typedef __attribute__((ext_vector_type(4))) __bf16 bf16x4;
typedef __attribute__((ext_vector_type(8))) __bf16 bf16x8;
typedef __attribute__((ext_vector_type(4))) float f32x4;
typedef __attribute__((ext_vector_type(16))) float f32x16;

#define B_ 4
#define S_ 2048
#define H_ 16
#define D_ 64
#define E_ 1024

#define BM 256
#define BN 128
#define BK 64

__device__ __forceinline__ int imin(int a, int b) { return a < b ? a : b; }
__device__ __forceinline__ int imax(int a, int b) { return a > b ? a : b; }

__device__ __forceinline__ void gload_lds16(const void* g, void* l) {
  __builtin_amdgcn_global_load_lds(
      (const __attribute__((address_space(1))) void*)g,
      (__attribute__((address_space(3))) void*)l, 16, 0, 0);
}

// ------ fused f32 -> bf16 convert for x (4096 blk), Wqkv (1536), Wout (512) --
__global__ __launch_bounds__(256) void cvt3_kernel(
    const float* __restrict__ x, bf16* __restrict__ xb,
    const float* __restrict__ wqkv, bf16* __restrict__ wqkvb,
    const float* __restrict__ wout, bf16* __restrict__ woutb) {
  const int bid = blockIdx.x;
  const float* in;
  bf16* out;
  int idx;
  if (bid < 4096) { in = x; out = xb; idx = bid; }
  else if (bid < 5632) { in = wqkv; out = wqkvb; idx = bid - 4096; }
  else { in = wout; out = woutb; idx = bid - 5632; }
  const int i = (idx * 256 + threadIdx.x) * 8;
  float4 v0 = *(const float4*)(in + i);
  float4 v1 = *(const float4*)(in + i + 4);
  bf16x8 o;
  o[0] = (bf16)v0.x; o[1] = (bf16)v0.y; o[2] = (bf16)v0.z; o[3] = (bf16)v0.w;
  o[4] = (bf16)v1.x; o[5] = (bf16)v1.y; o[6] = (bf16)v1.z; o[7] = (bf16)v1.w;
  *(bf16x8*)(out + i) = o;
}

// ------------- NT bf16 GEMM, 256x128 tile, 3-buf distance-2 pipeline -------
// Round-8 version (best measured QKV = 75.2 us, SQ_LDS_BANK_CONFLICT = 0).
__global__ __launch_bounds__(512, 1) void gemm_pipe(
    const bf16* __restrict__ A, const bf16* __restrict__ Bm,
    int M, int N, int K, int mode,
    bf16* __restrict__ qd, bf16* __restrict__ kd, bf16* __restrict__ vtd,
    float* __restrict__ outf) {
  __shared__ __align__(16) bf16 As[3][BM * BK];
  __shared__ __align__(16) bf16 Bs[3][BN * BK];
  const int tid = threadIdx.x;
  const int wave = tid >> 6, lane = tid & 63;
  const int l15 = lane & 15, l4 = lane >> 4;
  const int wm = (wave >> 1) * 64;
  const int wn = (wave & 1) * 64;

  const int nwg = gridDim.x * gridDim.y;
  const int fid = blockIdx.y * gridDim.x + blockIdx.x;
  const int chunk = nwg >> 3;
  const int swz = (fid & 7) * chunk + (fid >> 3);
  const int tn = swz % gridDim.x;
  const int tm = swz / gridDim.x;

  const bf16* Abase = A + (size_t)tm * BM * K;
  const bf16* Bbase = Bm + (size_t)tn * BN * K;

  f32x4 acc[4][4];
#pragma unroll
  for (int i = 0; i < 4; ++i)
#pragma unroll
    for (int j = 0; j < 4; ++j)
#pragma unroll
      for (int r = 0; r < 4; ++r) acc[i][j][r] = 0.f;

  const int NT = K >> 6;

#define STAGE_A(sbuf, k0)                                                      \
  {                                                                            \
    _Pragma("unroll") for (int ld = 0; ld < 4; ++ld) {                         \
      const int idx = ld * 512 + tid;                                          \
      const int row = idx >> 3, g = idx & 7;                                   \
      const int gs = g ^ (row & 7);                                            \
      gload_lds16(Abase + (size_t)row * K + (k0) + gs * 8,                     \
                  As[sbuf] + (ld * 512 + wave * 64) * 8);                      \
    }                                                                          \
  }
#define STAGE_B(sbuf, k0)                                                      \
  {                                                                            \
    _Pragma("unroll") for (int ld = 0; ld < 2; ++ld) {                         \
      const int idx = ld * 512 + tid;                                          \
      const int row = idx >> 3, g = idx & 7;                                   \
      const int gs = g ^ (row & 7);                                            \
      gload_lds16(Bbase + (size_t)row * K + (k0) + gs * 8,                     \
                  Bs[sbuf] + (ld * 512 + wave * 64) * 8);                      \
    }                                                                          \
  }

  STAGE_A(0, 0); STAGE_B(0, 0);
  STAGE_A(1, BK); STAGE_B(1, BK);
  asm volatile("s_waitcnt vmcnt(6)" ::: "memory");
  __builtin_amdgcn_s_barrier();

  int p = 0;
  for (int t = 0; t < NT; ++t) {
    const bf16* Ap = As[p];
    const bf16* Bp = Bs[p];
    const int sb = (p + 2 >= 3) ? p - 1 : p + 2;
    const int sk0 = ((t + 2 < NT) ? t + 2 : NT - 1) * BK;

    bf16x8 a[4], bfr[4];
#pragma unroll
    for (int i = 0; i < 4; ++i) {
      const int ra = wm + i * 16 + l15;
      a[i] = *(const bf16x8*)(Ap + ra * 64 + ((l4 ^ (ra & 7)) * 8));
      const int rb = wn + i * 16 + l15;
      bfr[i] = *(const bf16x8*)(Bp + rb * 64 + ((l4 ^ (rb & 7)) * 8));
    }
    STAGE_A(sb, sk0);
    __builtin_amdgcn_s_setprio(1);
#pragma unroll
    for (int i = 0; i < 4; ++i)
#pragma unroll
      for (int j = 0; j < 4; ++j)
        acc[i][j] = __builtin_amdgcn_mfma_f32_16x16x32_bf16(a[i], bfr[j],
                                                            acc[i][j], 0, 0, 0);
    __builtin_amdgcn_s_setprio(0);
#pragma unroll
    for (int i = 0; i < 4; ++i) {
      const int ra = wm + i * 16 + l15;
      a[i] = *(const bf16x8*)(Ap + ra * 64 + (((4 + l4) ^ (ra & 7)) * 8));
      const int rb = wn + i * 16 + l15;
      bfr[i] = *(const bf16x8*)(Bp + rb * 64 + (((4 + l4) ^ (rb & 7)) * 8));
    }
    STAGE_B(sb, sk0);
    __builtin_amdgcn_s_setprio(1);
#pragma unroll
    for (int i = 0; i < 4; ++i)
#pragma unroll
      for (int j = 0; j < 4; ++j)
        acc[i][j] = __builtin_amdgcn_mfma_f32_16x16x32_bf16(a[i], bfr[j],
                                                            acc[i][j], 0, 0, 0);
    __builtin_amdgcn_s_setprio(0);

    asm volatile("s_waitcnt vmcnt(6)" ::: "memory");
    __builtin_amdgcn_s_barrier();
    p = (p + 1 >= 3) ? 0 : p + 1;
  }
#undef STAGE_A
#undef STAGE_B

  if (mode == 0) {
#pragma unroll
    for (int i = 0; i < 4; ++i) {
      const int m0 = tm * BM + wm + i * 16 + l4 * 4;
      const int b = m0 >> 11, s = m0 & (S_ - 1);
#pragma unroll
      for (int j = 0; j < 4; ++j) {
        const int n = tn * BN + wn + j * 16 + l15;
        const int which = n >> 10;
        const int hn = n & 1023;
        const int h = hn >> 6, d = hn & 63;
        const f32x4 av = acc[i][j];
        if (which == 0) {
#pragma unroll
          for (int r = 0; r < 4; ++r)
            qd[((size_t)(b * H_ + h) * S_ + (s + r)) * D_ + d] =
                (bf16)(av[r] * 0.125f);
        } else if (which == 1) {
#pragma unroll
          for (int r = 0; r < 4; ++r)
            kd[((size_t)(b * H_ + h) * S_ + (s + r)) * D_ + d] = (bf16)av[r];
        } else {
          bf16x4 pv;
#pragma unroll
          for (int r = 0; r < 4; ++r) pv[r] = (bf16)av[r];
          *(bf16x4*)(vtd + ((size_t)(b * H_ + h) * D_ + d) * S_ + s) = pv;
        }
      }
    }
  } else {
#pragma unroll
    for (int i = 0; i < 4; ++i) {
      const int m0 = tm * BM + wm + i * 16 + l4 * 4;
#pragma unroll
      for (int j = 0; j < 4; ++j) {
        const int n = tn * BN + wn + j * 16 + l15;
#pragma unroll
        for (int r = 0; r < 4; ++r) outf[(size_t)(m0 + r) * N + n] = acc[i][j][r];
      }
    }
  }
}

// ------- mean of v over all S: 256 blocks = 64 bh x 4 d-quarters ----------
__global__ __launch_bounds__(256) void meanv_kernel(const bf16* __restrict__ vt,
                                                    float* __restrict__ meanv) {
  const int bh = blockIdx.x >> 2, dq = blockIdx.x & 3;
  const int tid = threadIdx.x;
  const int dl = tid >> 4;
  const int sl = tid & 15;
  const int d = dq * 16 + dl;
  const bf16* row = vt + ((size_t)bh * D_ + d) * S_;
  float s = 0.f;
#pragma unroll
  for (int it = 0; it < 16; ++it) {
    bf16x8 v = *(const bf16x8*)(row + it * 128 + sl * 8);
#pragma unroll
    for (int j = 0; j < 8; ++j) s += (float)v[j];
  }
#pragma unroll
  for (int m = 1; m < 16; m <<= 1) s += __shfl_xor(s, m, 64);
  if (sl == 0) meanv[(size_t)bh * D_ + d] = s * (1.0f / (float)S_);
}

// -------- flash attention (round-7 version): 4 waves x 32 q-rows, KVBLK=64 --
// VGPR ~100, occupancy ~17% — best measured attn (~48 us in the 173.7 run).
__device__ __forceinline__ int pk2(float a, float b) {
  union { bf16x2 h; int i; } u;
  u.h[0] = (bf16)a; u.h[1] = (bf16)b;
  return u.i;
}

__global__ __launch_bounds__(256) void attn_kernel(
    const bf16* __restrict__ q, const bf16* __restrict__ k,
    const bf16* __restrict__ vt, const float* __restrict__ meanv,
    const int* __restrict__ seq_lengths, const int* __restrict__ wlp,
    const int* __restrict__ wrp, bf16* __restrict__ attn_out) {
  __shared__ __align__(16) bf16 Ks[2][64 * 64];
  __shared__ __align__(16) bf16 Vs[2][64 * 64];
  const int tid = threadIdx.x, wave = tid >> 6, lane = tid & 63;
  const int l31 = lane & 31, l5 = lane >> 5;
  const int bid0 = blockIdx.x;
  const int bid = (bid0 & 7) * 128 + (bid0 >> 3);
  const int bh = bid >> 4;
  const int g = bid & 15;
  const int b = bh >> 4, h = bh & 15;
  const int q0b = g * 128;
  const int q0w = q0b + wave * 32;
  const int seq_len = seq_lengths[b];
  const int wl = wlp[0], wr = wrp[0];

  const bf16* qbase = q + (size_t)bh * S_ * D_;
  const bf16* kbase = k + (size_t)bh * S_ * D_;
  const bf16* vtb = vt + (size_t)bh * D_ * S_;

  bf16x8 qa[4];
#pragma unroll
  for (int dg = 0; dg < 4; ++dg)
    qa[dg] = *(const bf16x8*)(qbase + (size_t)(q0w + l31) * D_ + dg * 16 + l5 * 8);

  const int hi_blk = (wr >= 0) ? imin(q0b + 127 + wr, S_ - 1) : (S_ - 1);
  const int end_blk = imin(hi_blk + 1, seq_len);
  const int lo_blk = (wl >= 0) ? imax(0, q0b - wl) : 0;
  const int beg_blk = lo_blk & ~63;
  const int ntb = (end_blk > beg_blk) ? ((end_blk - beg_blk + 63) >> 6) : 0;

  const int w_hi = (wr >= 0) ? (q0w + 31 + wr) : (S_ - 1);
  const int w_end = imin(w_hi + 1, seq_len);
  const int w_lo = (wl >= 0) ? imax(0, q0w - wl) : 0;

  f32x16 o0, o1;
#pragma unroll
  for (int r = 0; r < 16; ++r) { o0[r] = 0.f; o1[r] = 0.f; }
  float mrun = -1e30f, lrun = 0.f;

#define STAGE(bufb, kt0)                                                       \
  {                                                                            \
    _Pragma("unroll") for (int ld = 0; ld < 2; ++ld) {                         \
      const int idx = ld * 256 + tid;                                          \
      const int row = idx >> 3, gg = idx & 7;                                  \
      const int gs = gg ^ (row & 7);                                           \
      const int krow = imin((kt0) + row, S_ - 1);                              \
      gload_lds16(kbase + (size_t)krow * 64 + gs * 8, Ks[bufb] + idx * 8);     \
      const int vcol = imin((kt0) + gs * 8, S_ - 8);                           \
      gload_lds16(vtb + (size_t)row * S_ + vcol, Vs[bufb] + idx * 8);          \
    }                                                                          \
  }
#define LDS_K(bufb, row, gran)                                                 \
  (*(const bf16x8*)((const char*)(Ks[bufb]) + (row) * 128 +                    \
                    (((gran) ^ ((row) & 7)) << 4)))
#define LDS_V(bufb, row, gran)                                                 \
  (*(const bf16x8*)((const char*)(Vs[bufb]) + (row) * 128 +                    \
                    (((gran) ^ ((row) & 7)) << 4)))

  if (ntb > 0) STAGE(0, beg_blk);
  __syncthreads();

  for (int t = 0; t < ntb; ++t) {
    const int kt = beg_blk + t * 64;
    if (t + 1 < ntb) STAGE((t + 1) & 1, kt + 64);

    const bool active = (kt < w_end) && (kt + 63 >= w_lo);
    if (active) {
      const int bufb = t & 1;
      f32x16 sf0, sf1;
#pragma unroll
      for (int r = 0; r < 16; ++r) { sf0[r] = 0.f; sf1[r] = 0.f; }
#pragma unroll
      for (int dg = 0; dg < 4; ++dg) {
        bf16x8 kb0 = LDS_K(bufb, l31, dg * 2 + l5);
        bf16x8 kb1 = LDS_K(bufb, 32 + l31, dg * 2 + l5);
        sf0 = __builtin_amdgcn_mfma_f32_32x32x16_bf16(kb0, qa[dg], sf0, 0, 0, 0);
        sf1 = __builtin_amdgcn_mfma_f32_32x32x16_bf16(kb1, qa[dg], sf1, 0, 0, 0);
      }

      bool allv = (kt + 63 < seq_len);
      if (wr >= 0) allv = allv && (kt + 63 <= q0w + wr);
      if (wl >= 0) allv = allv && (kt >= q0w + 31 - wl);
      if (!allv) {
        const int qrow = q0w + l31;
#pragma unroll
        for (int hh = 0; hh < 2; ++hh)
#pragma unroll
          for (int r = 0; r < 16; ++r) {
            const int key = kt + hh * 32 + (r & 3) + 8 * (r >> 2) + 4 * l5;
            bool valid = (key < seq_len);
            if (wr >= 0) valid = valid && (key <= qrow + wr);
            if (wl >= 0) valid = valid && (key >= qrow - wl);
            if (hh == 0) sf0[r] = valid ? sf0[r] : -1e30f;
            else sf1[r] = valid ? sf1[r] : -1e30f;
          }
      }
      float tmax = -1e30f;
#pragma unroll
      for (int r = 0; r < 16; ++r) {
        tmax = fmaxf(tmax, sf0[r]);
        tmax = fmaxf(tmax, sf1[r]);
      }
      tmax = fmaxf(tmax, __shfl_xor(tmax, 32, 64));

      if (!__all(tmax <= mrun + 8.0f)) {
        const float mnew = fmaxf(mrun, tmax);
        const float corr = __expf(mrun - mnew);
        mrun = mnew;
        lrun *= corr;
#pragma unroll
        for (int r = 0; r < 16; ++r) { o0[r] *= corr; o1[r] *= corr; }
      }

      float lsum = 0.f;
#pragma unroll
      for (int r = 0; r < 16; ++r) {
        const float e0 = (sf0[r] <= -1e29f) ? 0.f : __expf(sf0[r] - mrun);
        const float e1 = (sf1[r] <= -1e29f) ? 0.f : __expf(sf1[r] - mrun);
        sf0[r] = e0; sf1[r] = e1;
        lsum += e0 + e1;
      }
      lsum += __shfl_xor(lsum, 32, 64);
      lrun += lsum;

      bf16x8 pb[4];
#pragma unroll
      for (int kg = 0; kg < 4; ++kg) {
        const int base = (kg & 1) * 8;
        float p0, p1, p2, p3, p4, p5, p6, p7;
        if (kg < 2) {
          p0 = sf0[base + 0]; p1 = sf0[base + 1]; p2 = sf0[base + 2];
          p3 = sf0[base + 3]; p4 = sf0[base + 4]; p5 = sf0[base + 5];
          p6 = sf0[base + 6]; p7 = sf0[base + 7];
        } else {
          p0 = sf1[base + 0]; p1 = sf1[base + 1]; p2 = sf1[base + 2];
          p3 = sf1[base + 3]; p4 = sf1[base + 4]; p5 = sf1[base + 5];
          p6 = sf1[base + 6]; p7 = sf1[base + 7];
        }
        const int w0 = pk2(p0, p1);
        const int w1 = pk2(p2, p3);
        const int w2 = pk2(p4, p5);
        const int w3 = pk2(p6, p7);
        auto r02 = __builtin_amdgcn_permlane32_swap(w0, w2, false, false);
        auto r13 = __builtin_amdgcn_permlane32_swap(w1, w3, false, false);
        union { int i[4]; bf16x8 v; } u;
        u.i[0] = r02[0]; u.i[1] = r13[0]; u.i[2] = r02[1]; u.i[3] = r13[1];
        pb[kg] = u.v;
      }

#pragma unroll
      for (int kg = 0; kg < 4; ++kg) {
        bf16x8 va0 = LDS_V(bufb, l31, kg * 2 + l5);
        bf16x8 va1 = LDS_V(bufb, 32 + l31, kg * 2 + l5);
        o0 = __builtin_amdgcn_mfma_f32_32x32x16_bf16(va0, pb[kg], o0, 0, 0, 0);
        o1 = __builtin_amdgcn_mfma_f32_32x32x16_bf16(va1, pb[kg], o1, 0, 0, 0);
      }
    }
    __syncthreads();
  }
#undef STAGE
#undef LDS_K
#undef LDS_V

  const int qrow = q0w + l31;
  bf16* outp = attn_out + ((size_t)(b * S_ + qrow)) * E_ + h * 64;
  if (lrun > 0.f) {
    const float inv = 1.0f / lrun;
#pragma unroll
    for (int dg2 = 0; dg2 < 2; ++dg2) {
      const f32x16& o = dg2 ? o1 : o0;
#pragma unroll
      for (int rg = 0; rg < 4; ++rg) {
        const int d0 = dg2 * 32 + 8 * rg + 4 * l5;
        bf16x4 ov;
#pragma unroll
        for (int j = 0; j < 4; ++j) ov[j] = (bf16)(o[rg * 4 + j] * inv);
        *(bf16x4*)(outp + d0) = ov;
      }
    }
  } else {
    const float* mv = meanv + (size_t)bh * D_;
#pragma unroll
    for (int dg2 = 0; dg2 < 2; ++dg2)
#pragma unroll
      for (int rg = 0; rg < 4; ++rg) {
        const int d0 = dg2 * 32 + 8 * rg + 4 * l5;
        bf16x4 ov;
#pragma unroll
        for (int j = 0; j < 4; ++j) ov[j] = (bf16)mv[d0 + j];
        *(bf16x4*)(outp + d0) = ov;
      }
  }
}

// ---------------- launch ----------------
extern "C" void kernel_launch(void* const* d_in, const int* in_sizes, int n_in,
                              void* d_out, int out_size, void* d_ws, size_t ws_size,
                              hipStream_t stream) {
  const float* x = (const float*)d_in[0];
  const float* Wqkv = (const float*)d_in[1];
  const float* Wout = (const float*)d_in[2];
  const int* seq_lengths = (const int*)d_in[3];
  const int* wl = (const int*)d_in[4];
  const int* wr = (const int*)d_in[5];
  float* out = (float*)d_out;

  char* ws = (char*)d_ws;
  bf16* xb = (bf16*)ws;      ws += (size_t)8192 * 1024 * 2;
  bf16* wqkvb = (bf16*)ws;   ws += (size_t)3072 * 1024 * 2;
  bf16* woutb = (bf16*)ws;   ws += (size_t)1024 * 1024 * 2;
  bf16* qd = (bf16*)ws;      ws += (size_t)B_ * H_ * S_ * D_ * 2;
  bf16* kd = (bf16*)ws;      ws += (size_t)B_ * H_ * S_ * D_ * 2;
  bf16* vtd = (bf16*)ws;     ws += (size_t)B_ * H_ * S_ * D_ * 2;
  bf16* attn = (bf16*)ws;    ws += (size_t)8192 * 1024 * 2;
  float* meanv = (float*)ws; ws += (size_t)B_ * H_ * D_ * 4;

  cvt3_kernel<<<6144, 256, 0, stream>>>(x, xb, Wqkv, wqkvb, Wout, woutb);

  gemm_pipe<<<dim3(24, 32), 512, 0, stream>>>(xb, wqkvb, 8192, 3072, 1024, 0,
                                              qd, kd, vtd, nullptr);
  meanv_kernel<<<256, 256, 0, stream>>>(vtd, meanv);
  attn_kernel<<<1024, 256, 0, stream>>>(qd, kd, vtd, meanv, seq_lengths, wl, wr,
                                        attn);
  gemm_pipe<<<dim3(8, 32), 512, 0, stream>>>(attn, woutb, 8192, 1024, 1024, 1,
                                             nullptr, nullptr, nullptr, out);
}

// Round 19
// 167.826 us; speedup vs baseline: 1.3140x; 1.0059x over previous
//
#include <hip/hip_runtime.h>

typedef __bf16 bf16;
typedef __attribute__((ext_vector_type(2))) __bf16 bf16x2;
typedef __attribute__((ext_vector_type(4))) __bf16 bf16x4;
typedef __attribute__((ext_vector_type(8))) __bf16 bf16x8;
typedef __attribute__((ext_vector_type(4))) float f32x4;
typedef __attribute__((ext_vector_type(16))) float f32x16;

#define B_ 4
#define S_ 2048
#define H_ 16
#define D_ 64
#define E_ 1024

#define BM 256
#define BN 128
#define BK 64

__device__ __forceinline__ int imin(int a, int b) { return a < b ? a : b; }
__device__ __forceinline__ int imax(int a, int b) { return a > b ? a : b; }

__device__ __forceinline__ void gload_lds16(const void* g, void* l) {
  __builtin_amdgcn_global_load_lds(
      (const __attribute__((address_space(1))) void*)g,
      (__attribute__((address_space(3))) void*)l, 16, 0, 0);
}

// ------ fused f32 -> bf16 convert for x (4096 blk), Wqkv (1536), Wout (512) --
__global__ __launch_bounds__(256) void cvt3_kernel(
    const float* __restrict__ x, bf16* __restrict__ xb,
    const float* __restrict__ wqkv, bf16* __restrict__ wqkvb,
    const float* __restrict__ wout, bf16* __restrict__ woutb) {
  const int bid = blockIdx.x;
  const float* in;
  bf16* out;
  int idx;
  if (bid < 4096) { in = x; out = xb; idx = bid; }
  else if (bid < 5632) { in = wqkv; out = wqkvb; idx = bid - 4096; }
  else { in = wout; out = woutb; idx = bid - 5632; }
  const int i = (idx * 256 + threadIdx.x) * 8;
  float4 v0 = *(const float4*)(in + i);
  float4 v1 = *(const float4*)(in + i + 4);
  bf16x8 o;
  o[0] = (bf16)v0.x; o[1] = (bf16)v0.y; o[2] = (bf16)v0.z; o[3] = (bf16)v0.w;
  o[4] = (bf16)v1.x; o[5] = (bf16)v1.y; o[6] = (bf16)v1.z; o[7] = (bf16)v1.w;
  *(bf16x8*)(out + i) = o;
}

// ------------- NT bf16 GEMM, 256x128 tile, 3-buf distance-2 pipeline -------
// Round-8 version (best measured QKV = 75.2 us, SQ_LDS_BANK_CONFLICT = 0).
__global__ __launch_bounds__(512, 1) void gemm_pipe(
    const bf16* __restrict__ A, const bf16* __restrict__ Bm,
    int M, int N, int K, int mode,
    bf16* __restrict__ qd, bf16* __restrict__ kd, bf16* __restrict__ vtd,
    float* __restrict__ outf) {
  __shared__ __align__(16) bf16 As[3][BM * BK];
  __shared__ __align__(16) bf16 Bs[3][BN * BK];
  const int tid = threadIdx.x;
  const int wave = tid >> 6, lane = tid & 63;
  const int l15 = lane & 15, l4 = lane >> 4;
  const int wm = (wave >> 1) * 64;
  const int wn = (wave & 1) * 64;

  const int nwg = gridDim.x * gridDim.y;
  const int fid = blockIdx.y * gridDim.x + blockIdx.x;
  const int chunk = nwg >> 3;
  const int swz = (fid & 7) * chunk + (fid >> 3);
  const int tn = swz % gridDim.x;
  const int tm = swz / gridDim.x;

  const bf16* Abase = A + (size_t)tm * BM * K;
  const bf16* Bbase = Bm + (size_t)tn * BN * K;

  f32x4 acc[4][4];
#pragma unroll
  for (int i = 0; i < 4; ++i)
#pragma unroll
    for (int j = 0; j < 4; ++j)
#pragma unroll
      for (int r = 0; r < 4; ++r) acc[i][j][r] = 0.f;

  const int NT = K >> 6;

#define STAGE_A(sbuf, k0)                                                      \
  {                                                                            \
    _Pragma("unroll") for (int ld = 0; ld < 4; ++ld) {                         \
      const int idx = ld * 512 + tid;                                          \
      const int row = idx >> 3, g = idx & 7;                                   \
      const int gs = g ^ (row & 7);                                            \
      gload_lds16(Abase + (size_t)row * K + (k0) + gs * 8,                     \
                  As[sbuf] + (ld * 512 + wave * 64) * 8);                      \
    }                                                                          \
  }
#define STAGE_B(sbuf, k0)                                                      \
  {                                                                            \
    _Pragma("unroll") for (int ld = 0; ld < 2; ++ld) {                         \
      const int idx = ld * 512 + tid;                                          \
      const int row = idx >> 3, g = idx & 7;                                   \
      const int gs = g ^ (row & 7);                                            \
      gload_lds16(Bbase + (size_t)row * K + (k0) + gs * 8,                     \
                  Bs[sbuf] + (ld * 512 + wave * 64) * 8);                      \
    }                                                                          \
  }

  STAGE_A(0, 0); STAGE_B(0, 0);
  STAGE_A(1, BK); STAGE_B(1, BK);
  asm volatile("s_waitcnt vmcnt(6)" ::: "memory");
  __builtin_amdgcn_s_barrier();

  int p = 0;
  for (int t = 0; t < NT; ++t) {
    const bf16* Ap = As[p];
    const bf16* Bp = Bs[p];
    const int sb = (p + 2 >= 3) ? p - 1 : p + 2;
    const int sk0 = ((t + 2 < NT) ? t + 2 : NT - 1) * BK;

    bf16x8 a[4], bfr[4];
#pragma unroll
    for (int i = 0; i < 4; ++i) {
      const int ra = wm + i * 16 + l15;
      a[i] = *(const bf16x8*)(Ap + ra * 64 + ((l4 ^ (ra & 7)) * 8));
      const int rb = wn + i * 16 + l15;
      bfr[i] = *(const bf16x8*)(Bp + rb * 64 + ((l4 ^ (rb & 7)) * 8));
    }
    STAGE_A(sb, sk0);
    __builtin_amdgcn_s_setprio(1);
#pragma unroll
    for (int i = 0; i < 4; ++i)
#pragma unroll
      for (int j = 0; j < 4; ++j)
        acc[i][j] = __builtin_amdgcn_mfma_f32_16x16x32_bf16(a[i], bfr[j],
                                                            acc[i][j], 0, 0, 0);
    __builtin_amdgcn_s_setprio(0);
#pragma unroll
    for (int i = 0; i < 4; ++i) {
      const int ra = wm + i * 16 + l15;
      a[i] = *(const bf16x8*)(Ap + ra * 64 + (((4 + l4) ^ (ra & 7)) * 8));
      const int rb = wn + i * 16 + l15;
      bfr[i] = *(const bf16x8*)(Bp + rb * 64 + (((4 + l4) ^ (rb & 7)) * 8));
    }
    STAGE_B(sb, sk0);
    __builtin_amdgcn_s_setprio(1);
#pragma unroll
    for (int i = 0; i < 4; ++i)
#pragma unroll
      for (int j = 0; j < 4; ++j)
        acc[i][j] = __builtin_amdgcn_mfma_f32_16x16x32_bf16(a[i], bfr[j],
                                                            acc[i][j], 0, 0, 0);
    __builtin_amdgcn_s_setprio(0);

    asm volatile("s_waitcnt vmcnt(6)" ::: "memory");
    __builtin_amdgcn_s_barrier();
    p = (p + 1 >= 3) ? 0 : p + 1;
  }
#undef STAGE_A
#undef STAGE_B

  if (mode == 0) {
#pragma unroll
    for (int i = 0; i < 4; ++i) {
      const int m0 = tm * BM + wm + i * 16 + l4 * 4;
      const int b = m0 >> 11, s = m0 & (S_ - 1);
#pragma unroll
      for (int j = 0; j < 4; ++j) {
        const int n = tn * BN + wn + j * 16 + l15;
        const int which = n >> 10;
        const int hn = n & 1023;
        const int h = hn >> 6, d = hn & 63;
        const f32x4 av = acc[i][j];
        if (which == 0) {
#pragma unroll
          for (int r = 0; r < 4; ++r)
            qd[((size_t)(b * H_ + h) * S_ + (s + r)) * D_ + d] =
                (bf16)(av[r] * 0.125f);
        } else if (which == 1) {
#pragma unroll
          for (int r = 0; r < 4; ++r)
            kd[((size_t)(b * H_ + h) * S_ + (s + r)) * D_ + d] = (bf16)av[r];
        } else {
          bf16x4 pv;
#pragma unroll
          for (int r = 0; r < 4; ++r) pv[r] = (bf16)av[r];
          *(bf16x4*)(vtd + ((size_t)(b * H_ + h) * D_ + d) * S_ + s) = pv;
        }
      }
    }
  } else {
#pragma unroll
    for (int i = 0; i < 4; ++i) {
      const int m0 = tm * BM + wm + i * 16 + l4 * 4;
#pragma unroll
      for (int j = 0; j < 4; ++j) {
        const int n = tn * BN + wn + j * 16 + l15;
#pragma unroll
        for (int r = 0; r < 4; ++r) outf[(size_t)(m0 + r) * N + n] = acc[i][j][r];
      }
    }
  }
}

// ------- mean of v over all S: 256 blocks = 64 bh x 4 d-quarters ----------
__global__ __launch_bounds__(256) void meanv_kernel(const bf16* __restrict__ vt,
                                                    float* __restrict__ meanv) {
  const int bh = blockIdx.x >> 2, dq = blockIdx.x & 3;
  const int tid = threadIdx.x;
  const int dl = tid >> 4;
  const int sl = tid & 15;
  const int d = dq * 16 + dl;
  const bf16* row = vt + ((size_t)bh * D_ + d) * S_;
  float s = 0.f;
#pragma unroll
  for (int it = 0; it < 16; ++it) {
    bf16x8 v = *(const bf16x8*)(row + it * 128 + sl * 8);
#pragma unroll
    for (int j = 0; j < 8; ++j) s += (float)v[j];
  }
#pragma unroll
  for (int m = 1; m < 16; m <<= 1) s += __shfl_xor(s, m, 64);
  if (sl == 0) meanv[(size_t)bh * D_ + d] = s * (1.0f / (float)S_);
}

// -------- flash attention: complementary-pair blocks (g, 15-g) -------------
// Each block runs TWO sequential flash passes over q-row groups g*128 and
// (15-g)*128 — per-block work tiles(g)+tiles(15-g) ~ constant, killing the
// ragged tail (r5 profile: occupancy 17% of a 50% cap from 2..11-tile spread).
// Inner body identical to the round-7 version (VGPR ~100, conflicts 0).
__device__ __forceinline__ int pk2(float a, float b) {
  union { bf16x2 h; int i; } u;
  u.h[0] = (bf16)a; u.h[1] = (bf16)b;
  return u.i;
}

__global__ __launch_bounds__(256) void attn_kernel(
    const bf16* __restrict__ q, const bf16* __restrict__ k,
    const bf16* __restrict__ vt, const float* __restrict__ meanv,
    const int* __restrict__ seq_lengths, const int* __restrict__ wlp,
    const int* __restrict__ wrp, bf16* __restrict__ attn_out) {
  __shared__ __align__(16) bf16 Ks[2][64 * 64];
  __shared__ __align__(16) bf16 Vs[2][64 * 64];
  const int tid = threadIdx.x, wave = tid >> 6, lane = tid & 63;
  const int l31 = lane & 31, l5 = lane >> 5;
  // XCD swizzle: 512 blocks, chunk 64
  const int bid0 = blockIdx.x;
  const int bid = (bid0 & 7) * 64 + (bid0 >> 3);
  const int bh = bid >> 3;  // 8 paired blocks per (b,h)
  const int gp = bid & 7;
  const int b = bh >> 4, h = bh & 15;
  const int seq_len = seq_lengths[b];
  const int wl = wlp[0], wr = wrp[0];

  const bf16* qbase = q + (size_t)bh * S_ * D_;
  const bf16* kbase = k + (size_t)bh * S_ * D_;
  const bf16* vtb = vt + (size_t)bh * D_ * S_;

#define STAGE(bufb, kt0)                                                       \
  {                                                                            \
    _Pragma("unroll") for (int ld = 0; ld < 2; ++ld) {                         \
      const int idx = ld * 256 + tid;                                          \
      const int row = idx >> 3, gg = idx & 7;                                  \
      const int gs = gg ^ (row & 7);                                           \
      const int krow = imin((kt0) + row, S_ - 1);                              \
      gload_lds16(kbase + (size_t)krow * 64 + gs * 8, Ks[bufb] + idx * 8);     \
      const int vcol = imin((kt0) + gs * 8, S_ - 8);                           \
      gload_lds16(vtb + (size_t)row * S_ + vcol, Vs[bufb] + idx * 8);          \
    }                                                                          \
  }
#define LDS_K(bufb, row, gran)                                                 \
  (*(const bf16x8*)((const char*)(Ks[bufb]) + (row) * 128 +                    \
                    (((gran) ^ ((row) & 7)) << 4)))
#define LDS_V(bufb, row, gran)                                                 \
  (*(const bf16x8*)((const char*)(Vs[bufb]) + (row) * 128 +                    \
                    (((gran) ^ ((row) & 7)) << 4)))

  for (int seg = 0; seg < 2; ++seg) {
    const int g = seg ? (15 - gp) : gp;
    const int q0b = g * 128;
    const int q0w = q0b + wave * 32;

    bf16x8 qa[4];
#pragma unroll
    for (int dg = 0; dg < 4; ++dg)
      qa[dg] = *(const bf16x8*)(qbase + (size_t)(q0w + l31) * D_ +
                                dg * 16 + l5 * 8);

    const int hi_blk = (wr >= 0) ? imin(q0b + 127 + wr, S_ - 1) : (S_ - 1);
    const int end_blk = imin(hi_blk + 1, seq_len);
    const int lo_blk = (wl >= 0) ? imax(0, q0b - wl) : 0;
    const int beg_blk = lo_blk & ~63;
    const int ntb = (end_blk > beg_blk) ? ((end_blk - beg_blk + 63) >> 6) : 0;

    const int w_hi = (wr >= 0) ? (q0w + 31 + wr) : (S_ - 1);
    const int w_end = imin(w_hi + 1, seq_len);
    const int w_lo = (wl >= 0) ? imax(0, q0w - wl) : 0;

    f32x16 o0, o1;
#pragma unroll
    for (int r = 0; r < 16; ++r) { o0[r] = 0.f; o1[r] = 0.f; }
    float mrun = -1e30f, lrun = 0.f;

    if (ntb > 0) STAGE(0, beg_blk);
    __syncthreads();

    for (int t = 0; t < ntb; ++t) {
      const int kt = beg_blk + t * 64;
      if (t + 1 < ntb) STAGE((t + 1) & 1, kt + 64);

      const bool active = (kt < w_end) && (kt + 63 >= w_lo);
      if (active) {
        const int bufb = t & 1;
        f32x16 sf0, sf1;
#pragma unroll
        for (int r = 0; r < 16; ++r) { sf0[r] = 0.f; sf1[r] = 0.f; }
#pragma unroll
        for (int dg = 0; dg < 4; ++dg) {
          bf16x8 kb0 = LDS_K(bufb, l31, dg * 2 + l5);
          bf16x8 kb1 = LDS_K(bufb, 32 + l31, dg * 2 + l5);
          sf0 = __builtin_amdgcn_mfma_f32_32x32x16_bf16(kb0, qa[dg], sf0, 0, 0, 0);
          sf1 = __builtin_amdgcn_mfma_f32_32x32x16_bf16(kb1, qa[dg], sf1, 0, 0, 0);
        }

        bool allv = (kt + 63 < seq_len);
        if (wr >= 0) allv = allv && (kt + 63 <= q0w + wr);
        if (wl >= 0) allv = allv && (kt >= q0w + 31 - wl);
        if (!allv) {
          const int qrow = q0w + l31;
#pragma unroll
          for (int hh = 0; hh < 2; ++hh)
#pragma unroll
            for (int r = 0; r < 16; ++r) {
              const int key = kt + hh * 32 + (r & 3) + 8 * (r >> 2) + 4 * l5;
              bool valid = (key < seq_len);
              if (wr >= 0) valid = valid && (key <= qrow + wr);
              if (wl >= 0) valid = valid && (key >= qrow - wl);
              if (hh == 0) sf0[r] = valid ? sf0[r] : -1e30f;
              else sf1[r] = valid ? sf1[r] : -1e30f;
            }
        }
        float tmax = -1e30f;
#pragma unroll
        for (int r = 0; r < 16; ++r) {
          tmax = fmaxf(tmax, sf0[r]);
          tmax = fmaxf(tmax, sf1[r]);
        }
        tmax = fmaxf(tmax, __shfl_xor(tmax, 32, 64));

        if (!__all(tmax <= mrun + 8.0f)) {
          const float mnew = fmaxf(mrun, tmax);
          const float corr = __expf(mrun - mnew);
          mrun = mnew;
          lrun *= corr;
#pragma unroll
          for (int r = 0; r < 16; ++r) { o0[r] *= corr; o1[r] *= corr; }
        }

        float lsum = 0.f;
#pragma unroll
        for (int r = 0; r < 16; ++r) {
          const float e0 = (sf0[r] <= -1e29f) ? 0.f : __expf(sf0[r] - mrun);
          const float e1 = (sf1[r] <= -1e29f) ? 0.f : __expf(sf1[r] - mrun);
          sf0[r] = e0; sf1[r] = e1;
          lsum += e0 + e1;
        }
        lsum += __shfl_xor(lsum, 32, 64);
        lrun += lsum;

        bf16x8 pb[4];
#pragma unroll
        for (int kg = 0; kg < 4; ++kg) {
          const int base = (kg & 1) * 8;
          float p0, p1, p2, p3, p4, p5, p6, p7;
          if (kg < 2) {
            p0 = sf0[base + 0]; p1 = sf0[base + 1]; p2 = sf0[base + 2];
            p3 = sf0[base + 3]; p4 = sf0[base + 4]; p5 = sf0[base + 5];
            p6 = sf0[base + 6]; p7 = sf0[base + 7];
          } else {
            p0 = sf1[base + 0]; p1 = sf1[base + 1]; p2 = sf1[base + 2];
            p3 = sf1[base + 3]; p4 = sf1[base + 4]; p5 = sf1[base + 5];
            p6 = sf1[base + 6]; p7 = sf1[base + 7];
          }
          const int w0 = pk2(p0, p1);
          const int w1 = pk2(p2, p3);
          const int w2 = pk2(p4, p5);
          const int w3 = pk2(p6, p7);
          auto r02 = __builtin_amdgcn_permlane32_swap(w0, w2, false, false);
          auto r13 = __builtin_amdgcn_permlane32_swap(w1, w3, false, false);
          union { int i[4]; bf16x8 v; } u;
          u.i[0] = r02[0]; u.i[1] = r13[0]; u.i[2] = r02[1]; u.i[3] = r13[1];
          pb[kg] = u.v;
        }

#pragma unroll
        for (int kg = 0; kg < 4; ++kg) {
          bf16x8 va0 = LDS_V(bufb, l31, kg * 2 + l5);
          bf16x8 va1 = LDS_V(bufb, 32 + l31, kg * 2 + l5);
          o0 = __builtin_amdgcn_mfma_f32_32x32x16_bf16(va0, pb[kg], o0, 0, 0, 0);
          o1 = __builtin_amdgcn_mfma_f32_32x32x16_bf16(va1, pb[kg], o1, 0, 0, 0);
        }
      }
      __syncthreads();
    }

    // ---- epilogue for this segment ----
    const int qrow = q0w + l31;
    bf16* outp = attn_out + ((size_t)(b * S_ + qrow)) * E_ + h * 64;
    if (lrun > 0.f) {
      const float inv = 1.0f / lrun;
#pragma unroll
      for (int dg2 = 0; dg2 < 2; ++dg2) {
        const f32x16& o = dg2 ? o1 : o0;
#pragma unroll
        for (int rg = 0; rg < 4; ++rg) {
          const int d0 = dg2 * 32 + 8 * rg + 4 * l5;
          bf16x4 ov;
#pragma unroll
          for (int j = 0; j < 4; ++j) ov[j] = (bf16)(o[rg * 4 + j] * inv);
          *(bf16x4*)(outp + d0) = ov;
        }
      }
    } else {
      const float* mv = meanv + (size_t)bh * D_;
#pragma unroll
      for (int dg2 = 0; dg2 < 2; ++dg2)
#pragma unroll
        for (int rg = 0; rg < 4; ++rg) {
          const int d0 = dg2 * 32 + 8 * rg + 4 * l5;
          bf16x4 ov;
#pragma unroll
          for (int j = 0; j < 4; ++j) ov[j] = (bf16)mv[d0 + j];
          *(bf16x4*)(outp + d0) = ov;
        }
    }
    __syncthreads();  // fence LDS reuse before next segment's STAGE
  }
#undef STAGE
#undef LDS_K
#undef LDS_V
}

// ---------------- launch ----------------
extern "C" void kernel_launch(void* const* d_in, const int* in_sizes, int n_in,
                              void* d_out, int out_size, void* d_ws, size_t ws_size,
                              hipStream_t stream) {
  const float* x = (const float*)d_in[0];
  const float* Wqkv = (const float*)d_in[1];
  const float* Wout = (const float*)d_in[2];
  const int* seq_lengths = (const int*)d_in[3];
  const int* wl = (const int*)d_in[4];
  const int* wr = (const int*)d_in[5];
  float* out = (float*)d_out;

  char* ws = (char*)d_ws;
  bf16* xb = (bf16*)ws;      ws += (size_t)8192 * 1024 * 2;
  bf16* wqkvb = (bf16*)ws;   ws += (size_t)3072 * 1024 * 2;
  bf16* woutb = (bf16*)ws;   ws += (size_t)1024 * 1024 * 2;
  bf16* qd = (bf16*)ws;      ws += (size_t)B_ * H_ * S_ * D_ * 2;
  bf16* kd = (bf16*)ws;      ws += (size_t)B_ * H_ * S_ * D_ * 2;
  bf16* vtd = (bf16*)ws;     ws += (size_t)B_ * H_ * S_ * D_ * 2;
  bf16* attn = (bf16*)ws;    ws += (size_t)8192 * 1024 * 2;
  float* meanv = (float*)ws; ws += (size_t)B_ * H_ * D_ * 4;

  cvt3_kernel<<<6144, 256, 0, stream>>>(x, xb, Wqkv, wqkvb, Wout, woutb);

  gemm_pipe<<<dim3(24, 32), 512, 0, stream>>>(xb, wqkvb, 8192, 3072, 1024, 0,
                                              qd, kd, vtd, nullptr);
  meanv_kernel<<<256, 256, 0, stream>>>(vtd, meanv);
  attn_kernel<<<512, 256, 0, stream>>>(qd, kd, vtd, meanv, seq_lengths, wl, wr,
                                       attn);
  gemm_pipe<<<dim3(8, 32), 512, 0, stream>>>(attn, woutb, 8192, 1024, 1024, 1,
                                             nullptr, nullptr, nullptr, out);
}

// Round 20
// 159.492 us; speedup vs baseline: 1.3826x; 1.0523x over previous
//
#include <hip/hip_runtime.h>

typedef __bf16 bf16;
typedef __attribute__((ext_vector_type(2))) __bf16 bf16x2;
typedef __attribute__((ext_vector_type(4))) __bf16 bf16x4;
typedef __attribute__((ext_vector_type(8))) __bf16 bf16x8;
typedef __attribute__((ext_vector_type(4))) float f32x4;
typedef __attribute__((ext_vector_type(16))) float f32x16;

#define B_ 4
#define S_ 2048
#define H_ 16
#define D_ 64
#define E_ 1024

#define BM 256
#define BN 128
#define BK 64

__device__ __forceinline__ int imin(int a, int b) { return a < b ? a : b; }
__device__ __forceinline__ int imax(int a, int b) { return a > b ? a : b; }

__device__ __forceinline__ void gload_lds16(const void* g, void* l) {
  __builtin_amdgcn_global_load_lds(
      (const __attribute__((address_space(1))) void*)g,
      (__attribute__((address_space(3))) void*)l, 16, 0, 0);
}

// ------ fused f32 -> bf16 convert for x (4096 blk), Wqkv (1536), Wout (512) --
__global__ __launch_bounds__(256) void cvt3_kernel(
    const float* __restrict__ x, bf16* __restrict__ xb,
    const float* __restrict__ wqkv, bf16* __restrict__ wqkvb,
    const float* __restrict__ wout, bf16* __restrict__ woutb) {
  const int bid = blockIdx.x;
  const float* in;
  bf16* out;
  int idx;
  if (bid < 4096) { in = x; out = xb; idx = bid; }
  else if (bid < 5632) { in = wqkv; out = wqkvb; idx = bid - 4096; }
  else { in = wout; out = woutb; idx = bid - 5632; }
  const int i = (idx * 256 + threadIdx.x) * 8;
  float4 v0 = *(const float4*)(in + i);
  float4 v1 = *(const float4*)(in + i + 4);
  bf16x8 o;
  o[0] = (bf16)v0.x; o[1] = (bf16)v0.y; o[2] = (bf16)v0.z; o[3] = (bf16)v0.w;
  o[4] = (bf16)v1.x; o[5] = (bf16)v1.y; o[6] = (bf16)v1.z; o[7] = (bf16)v1.w;
  *(bf16x8*)(out + i) = o;
}

// ------------- NT bf16 GEMM, 256x128 tile, 3-buf distance-2 pipeline -------
// Round-8 version (best measured QKV = 75.2 us, SQ_LDS_BANK_CONFLICT = 0).
__global__ __launch_bounds__(512, 1) void gemm_pipe(
    const bf16* __restrict__ A, const bf16* __restrict__ Bm,
    int M, int N, int K, int mode,
    bf16* __restrict__ qd, bf16* __restrict__ kd, bf16* __restrict__ vtd,
    float* __restrict__ outf) {
  __shared__ __align__(16) bf16 As[3][BM * BK];
  __shared__ __align__(16) bf16 Bs[3][BN * BK];
  const int tid = threadIdx.x;
  const int wave = tid >> 6, lane = tid & 63;
  const int l15 = lane & 15, l4 = lane >> 4;
  const int wm = (wave >> 1) * 64;
  const int wn = (wave & 1) * 64;

  const int nwg = gridDim.x * gridDim.y;
  const int fid = blockIdx.y * gridDim.x + blockIdx.x;
  const int chunk = nwg >> 3;
  const int swz = (fid & 7) * chunk + (fid >> 3);
  const int tn = swz % gridDim.x;
  const int tm = swz / gridDim.x;

  const bf16* Abase = A + (size_t)tm * BM * K;
  const bf16* Bbase = Bm + (size_t)tn * BN * K;

  f32x4 acc[4][4];
#pragma unroll
  for (int i = 0; i < 4; ++i)
#pragma unroll
    for (int j = 0; j < 4; ++j)
#pragma unroll
      for (int r = 0; r < 4; ++r) acc[i][j][r] = 0.f;

  const int NT = K >> 6;

#define STAGE_A(sbuf, k0)                                                      \
  {                                                                            \
    _Pragma("unroll") for (int ld = 0; ld < 4; ++ld) {                         \
      const int idx = ld * 512 + tid;                                          \
      const int row = idx >> 3, g = idx & 7;                                   \
      const int gs = g ^ (row & 7);                                            \
      gload_lds16(Abase + (size_t)row * K + (k0) + gs * 8,                     \
                  As[sbuf] + (ld * 512 + wave * 64) * 8);                      \
    }                                                                          \
  }
#define STAGE_B(sbuf, k0)                                                      \
  {                                                                            \
    _Pragma("unroll") for (int ld = 0; ld < 2; ++ld) {                         \
      const int idx = ld * 512 + tid;                                          \
      const int row = idx >> 3, g = idx & 7;                                   \
      const int gs = g ^ (row & 7);                                            \
      gload_lds16(Bbase + (size_t)row * K + (k0) + gs * 8,                     \
                  Bs[sbuf] + (ld * 512 + wave * 64) * 8);                      \
    }                                                                          \
  }

  STAGE_A(0, 0); STAGE_B(0, 0);
  STAGE_A(1, BK); STAGE_B(1, BK);
  asm volatile("s_waitcnt vmcnt(6)" ::: "memory");
  __builtin_amdgcn_s_barrier();

  int p = 0;
  for (int t = 0; t < NT; ++t) {
    const bf16* Ap = As[p];
    const bf16* Bp = Bs[p];
    const int sb = (p + 2 >= 3) ? p - 1 : p + 2;
    const int sk0 = ((t + 2 < NT) ? t + 2 : NT - 1) * BK;

    bf16x8 a[4], bfr[4];
#pragma unroll
    for (int i = 0; i < 4; ++i) {
      const int ra = wm + i * 16 + l15;
      a[i] = *(const bf16x8*)(Ap + ra * 64 + ((l4 ^ (ra & 7)) * 8));
      const int rb = wn + i * 16 + l15;
      bfr[i] = *(const bf16x8*)(Bp + rb * 64 + ((l4 ^ (rb & 7)) * 8));
    }
    STAGE_A(sb, sk0);
    __builtin_amdgcn_s_setprio(1);
#pragma unroll
    for (int i = 0; i < 4; ++i)
#pragma unroll
      for (int j = 0; j < 4; ++j)
        acc[i][j] = __builtin_amdgcn_mfma_f32_16x16x32_bf16(a[i], bfr[j],
                                                            acc[i][j], 0, 0, 0);
    __builtin_amdgcn_s_setprio(0);
#pragma unroll
    for (int i = 0; i < 4; ++i) {
      const int ra = wm + i * 16 + l15;
      a[i] = *(const bf16x8*)(Ap + ra * 64 + (((4 + l4) ^ (ra & 7)) * 8));
      const int rb = wn + i * 16 + l15;
      bfr[i] = *(const bf16x8*)(Bp + rb * 64 + (((4 + l4) ^ (rb & 7)) * 8));
    }
    STAGE_B(sb, sk0);
    __builtin_amdgcn_s_setprio(1);
#pragma unroll
    for (int i = 0; i < 4; ++i)
#pragma unroll
      for (int j = 0; j < 4; ++j)
        acc[i][j] = __builtin_amdgcn_mfma_f32_16x16x32_bf16(a[i], bfr[j],
                                                            acc[i][j], 0, 0, 0);
    __builtin_amdgcn_s_setprio(0);

    asm volatile("s_waitcnt vmcnt(6)" ::: "memory");
    __builtin_amdgcn_s_barrier();
    p = (p + 1 >= 3) ? 0 : p + 1;
  }
#undef STAGE_A
#undef STAGE_B

  if (mode == 0) {
#pragma unroll
    for (int i = 0; i < 4; ++i) {
      const int m0 = tm * BM + wm + i * 16 + l4 * 4;
      const int b = m0 >> 11, s = m0 & (S_ - 1);
#pragma unroll
      for (int j = 0; j < 4; ++j) {
        const int n = tn * BN + wn + j * 16 + l15;
        const int which = n >> 10;
        const int hn = n & 1023;
        const int h = hn >> 6, d = hn & 63;
        const f32x4 av = acc[i][j];
        if (which == 0) {
#pragma unroll
          for (int r = 0; r < 4; ++r)
            qd[((size_t)(b * H_ + h) * S_ + (s + r)) * D_ + d] =
                (bf16)(av[r] * 0.125f);
        } else if (which == 1) {
#pragma unroll
          for (int r = 0; r < 4; ++r)
            kd[((size_t)(b * H_ + h) * S_ + (s + r)) * D_ + d] = (bf16)av[r];
        } else {
          bf16x4 pv;
#pragma unroll
          for (int r = 0; r < 4; ++r) pv[r] = (bf16)av[r];
          *(bf16x4*)(vtd + ((size_t)(b * H_ + h) * D_ + d) * S_ + s) = pv;
        }
      }
    }
  } else {
#pragma unroll
    for (int i = 0; i < 4; ++i) {
      const int m0 = tm * BM + wm + i * 16 + l4 * 4;
#pragma unroll
      for (int j = 0; j < 4; ++j) {
        const int n = tn * BN + wn + j * 16 + l15;
#pragma unroll
        for (int r = 0; r < 4; ++r) outf[(size_t)(m0 + r) * N + n] = acc[i][j][r];
      }
    }
  }
}

// ------- mean of v over all S: 256 blocks = 64 bh x 4 d-quarters ----------
__global__ __launch_bounds__(256) void meanv_kernel(const bf16* __restrict__ vt,
                                                    float* __restrict__ meanv) {
  const int bh = blockIdx.x >> 2, dq = blockIdx.x & 3;
  const int tid = threadIdx.x;
  const int dl = tid >> 4;
  const int sl = tid & 15;
  const int d = dq * 16 + dl;
  const bf16* row = vt + ((size_t)bh * D_ + d) * S_;
  float s = 0.f;
#pragma unroll
  for (int it = 0; it < 16; ++it) {
    bf16x8 v = *(const bf16x8*)(row + it * 128 + sl * 8);
#pragma unroll
    for (int j = 0; j < 8; ++j) s += (float)v[j];
  }
#pragma unroll
  for (int m = 1; m < 16; m <<= 1) s += __shfl_xor(s, m, 64);
  if (sl == 0) meanv[(size_t)bh * D_ + d] = s * (1.0f / (float)S_);
}

// -------- flash attention: pair blocks (g,15-g), KVBLK=128 staged ----------
// 128 keys staged per tile (K[128][64] 16KB + V^T[64][128] 16KB, dbuf=64KB,
// 2 blocks/CU) computed as two sequential 64-key sub-phases reusing sf0/sf1
// (VGPR-neutral). Barriers + stage bursts per key halve vs KVBLK=64.
__device__ __forceinline__ int pk2(float a, float b) {
  union { bf16x2 h; int i; } u;
  u.h[0] = (bf16)a; u.h[1] = (bf16)b;
  return u.i;
}

__global__ __launch_bounds__(256) void attn_kernel(
    const bf16* __restrict__ q, const bf16* __restrict__ k,
    const bf16* __restrict__ vt, const float* __restrict__ meanv,
    const int* __restrict__ seq_lengths, const int* __restrict__ wlp,
    const int* __restrict__ wrp, bf16* __restrict__ attn_out) {
  __shared__ __align__(16) bf16 Ks[2][128 * 64];
  __shared__ __align__(16) bf16 Vs[2][64 * 128];
  const int tid = threadIdx.x, wave = tid >> 6, lane = tid & 63;
  const int l31 = lane & 31, l5 = lane >> 5;
  // XCD swizzle: 512 blocks, chunk 64
  const int bid0 = blockIdx.x;
  const int bid = (bid0 & 7) * 64 + (bid0 >> 3);
  const int bh = bid >> 3;  // 8 paired blocks per (b,h)
  const int gp = bid & 7;
  const int b = bh >> 4, h = bh & 15;
  const int seq_len = seq_lengths[b];
  const int wl = wlp[0], wr = wrp[0];

  const bf16* qbase = q + (size_t)bh * S_ * D_;
  const bf16* kbase = k + (size_t)bh * S_ * D_;
  const bf16* vtb = vt + (size_t)bh * D_ * S_;

  // K: rows=key (8 granules/row, swz row&7). V^T: rows=d (16 granules, row&15).
#define STAGE(bufb, kt0)                                                       \
  {                                                                            \
    _Pragma("unroll") for (int ld = 0; ld < 4; ++ld) {                         \
      const int idx = ld * 256 + tid;                                          \
      const int krow_i = idx >> 3, kg_ = idx & 7;                              \
      const int kgs = kg_ ^ (krow_i & 7);                                      \
      const int krow = imin((kt0) + krow_i, S_ - 1);                           \
      gload_lds16(kbase + (size_t)krow * 64 + kgs * 8, Ks[bufb] + idx * 8);    \
      const int vrow = idx >> 4, vg_ = idx & 15;                               \
      const int vgs = vg_ ^ (vrow & 15);                                       \
      const int vcol = imin((kt0) + vgs * 8, S_ - 8);                          \
      gload_lds16(vtb + (size_t)vrow * S_ + vcol, Vs[bufb] + idx * 8);         \
    }                                                                          \
  }
#define LDS_K(bufb, row, gran)                                                 \
  (*(const bf16x8*)((const char*)(Ks[bufb]) + (row) * 128 +                    \
                    (((gran) ^ ((row) & 7)) << 4)))
#define LDS_V(bufb, row, gran)                                                 \
  (*(const bf16x8*)((const char*)(Vs[bufb]) + (row) * 256 +                    \
                    (((gran) ^ ((row) & 15)) << 4)))

  for (int seg = 0; seg < 2; ++seg) {
    const int g = seg ? (15 - gp) : gp;
    const int q0b = g * 128;
    const int q0w = q0b + wave * 32;

    bf16x8 qa[4];
#pragma unroll
    for (int dg = 0; dg < 4; ++dg)
      qa[dg] = *(const bf16x8*)(qbase + (size_t)(q0w + l31) * D_ +
                                dg * 16 + l5 * 8);

    const int hi_blk = (wr >= 0) ? imin(q0b + 127 + wr, S_ - 1) : (S_ - 1);
    const int end_blk = imin(hi_blk + 1, seq_len);
    const int lo_blk = (wl >= 0) ? imax(0, q0b - wl) : 0;
    const int beg_blk = lo_blk & ~127;
    const int ntb = (end_blk > beg_blk) ? ((end_blk - beg_blk + 127) >> 7) : 0;

    const int w_hi = (wr >= 0) ? (q0w + 31 + wr) : (S_ - 1);
    const int w_end = imin(w_hi + 1, seq_len);
    const int w_lo = (wl >= 0) ? imax(0, q0w - wl) : 0;

    f32x16 o0, o1;
#pragma unroll
    for (int r = 0; r < 16; ++r) { o0[r] = 0.f; o1[r] = 0.f; }
    float mrun = -1e30f, lrun = 0.f;

    if (ntb > 0) STAGE(0, beg_blk);
    __syncthreads();

    for (int t = 0; t < ntb; ++t) {
      const int kt = beg_blk + t * 128;
      if (t + 1 < ntb) STAGE((t + 1) & 1, kt + 128);
      const int bufb = t & 1;

#pragma unroll
      for (int kk = 0; kk < 2; ++kk) {
        const int kts = kt + kk * 64;
        const bool active = (kts < w_end) && (kts + 63 >= w_lo);
        if (active) {
          f32x16 sf0, sf1;
#pragma unroll
          for (int r = 0; r < 16; ++r) { sf0[r] = 0.f; sf1[r] = 0.f; }
#pragma unroll
          for (int dg = 0; dg < 4; ++dg) {
            bf16x8 kb0 = LDS_K(bufb, kk * 64 + l31, dg * 2 + l5);
            bf16x8 kb1 = LDS_K(bufb, kk * 64 + 32 + l31, dg * 2 + l5);
            sf0 = __builtin_amdgcn_mfma_f32_32x32x16_bf16(kb0, qa[dg], sf0,
                                                          0, 0, 0);
            sf1 = __builtin_amdgcn_mfma_f32_32x32x16_bf16(kb1, qa[dg], sf1,
                                                          0, 0, 0);
          }

          bool allv = (kts + 63 < seq_len);
          if (wr >= 0) allv = allv && (kts + 63 <= q0w + wr);
          if (wl >= 0) allv = allv && (kts >= q0w + 31 - wl);
          if (!allv) {
            const int qrow = q0w + l31;
#pragma unroll
            for (int hh = 0; hh < 2; ++hh)
#pragma unroll
              for (int r = 0; r < 16; ++r) {
                const int key = kts + hh * 32 + (r & 3) + 8 * (r >> 2) + 4 * l5;
                bool valid = (key < seq_len);
                if (wr >= 0) valid = valid && (key <= qrow + wr);
                if (wl >= 0) valid = valid && (key >= qrow - wl);
                if (hh == 0) sf0[r] = valid ? sf0[r] : -1e30f;
                else sf1[r] = valid ? sf1[r] : -1e30f;
              }
          }
          float tmax = -1e30f;
#pragma unroll
          for (int r = 0; r < 16; ++r) {
            tmax = fmaxf(tmax, sf0[r]);
            tmax = fmaxf(tmax, sf1[r]);
          }
          tmax = fmaxf(tmax, __shfl_xor(tmax, 32, 64));

          if (!__all(tmax <= mrun + 8.0f)) {
            const float mnew = fmaxf(mrun, tmax);
            const float corr = __expf(mrun - mnew);
            mrun = mnew;
            lrun *= corr;
#pragma unroll
            for (int r = 0; r < 16; ++r) { o0[r] *= corr; o1[r] *= corr; }
          }

          float lsum = 0.f;
#pragma unroll
          for (int r = 0; r < 16; ++r) {
            const float e0 = (sf0[r] <= -1e29f) ? 0.f : __expf(sf0[r] - mrun);
            const float e1 = (sf1[r] <= -1e29f) ? 0.f : __expf(sf1[r] - mrun);
            sf0[r] = e0; sf1[r] = e1;
            lsum += e0 + e1;
          }
          lsum += __shfl_xor(lsum, 32, 64);
          lrun += lsum;

          bf16x8 pb[4];
#pragma unroll
          for (int kg = 0; kg < 4; ++kg) {
            const int base = (kg & 1) * 8;
            float p0, p1, p2, p3, p4, p5, p6, p7;
            if (kg < 2) {
              p0 = sf0[base + 0]; p1 = sf0[base + 1]; p2 = sf0[base + 2];
              p3 = sf0[base + 3]; p4 = sf0[base + 4]; p5 = sf0[base + 5];
              p6 = sf0[base + 6]; p7 = sf0[base + 7];
            } else {
              p0 = sf1[base + 0]; p1 = sf1[base + 1]; p2 = sf1[base + 2];
              p3 = sf1[base + 3]; p4 = sf1[base + 4]; p5 = sf1[base + 5];
              p6 = sf1[base + 6]; p7 = sf1[base + 7];
            }
            const int w0 = pk2(p0, p1);
            const int w1 = pk2(p2, p3);
            const int w2 = pk2(p4, p5);
            const int w3 = pk2(p6, p7);
            auto r02 = __builtin_amdgcn_permlane32_swap(w0, w2, false, false);
            auto r13 = __builtin_amdgcn_permlane32_swap(w1, w3, false, false);
            union { int i[4]; bf16x8 v; } u;
            u.i[0] = r02[0]; u.i[1] = r13[0]; u.i[2] = r02[1]; u.i[3] = r13[1];
            pb[kg] = u.v;
          }

#pragma unroll
          for (int kg = 0; kg < 4; ++kg) {
            // key granule within the 128-wide V tile: kk*8 + kg*2 + l5
            bf16x8 va0 = LDS_V(bufb, l31, kk * 8 + kg * 2 + l5);
            bf16x8 va1 = LDS_V(bufb, 32 + l31, kk * 8 + kg * 2 + l5);
            o0 = __builtin_amdgcn_mfma_f32_32x32x16_bf16(va0, pb[kg], o0,
                                                         0, 0, 0);
            o1 = __builtin_amdgcn_mfma_f32_32x32x16_bf16(va1, pb[kg], o1,
                                                         0, 0, 0);
          }
        }
      }
      __syncthreads();
    }

    // ---- epilogue for this segment ----
    const int qrow = q0w + l31;
    bf16* outp = attn_out + ((size_t)(b * S_ + qrow)) * E_ + h * 64;
    if (lrun > 0.f) {
      const float inv = 1.0f / lrun;
#pragma unroll
      for (int dg2 = 0; dg2 < 2; ++dg2) {
        const f32x16& o = dg2 ? o1 : o0;
#pragma unroll
        for (int rg = 0; rg < 4; ++rg) {
          const int d0 = dg2 * 32 + 8 * rg + 4 * l5;
          bf16x4 ov;
#pragma unroll
          for (int j = 0; j < 4; ++j) ov[j] = (bf16)(o[rg * 4 + j] * inv);
          *(bf16x4*)(outp + d0) = ov;
        }
      }
    } else {
      const float* mv = meanv + (size_t)bh * D_;
#pragma unroll
      for (int dg2 = 0; dg2 < 2; ++dg2)
#pragma unroll
        for (int rg = 0; rg < 4; ++rg) {
          const int d0 = dg2 * 32 + 8 * rg + 4 * l5;
          bf16x4 ov;
#pragma unroll
          for (int j = 0; j < 4; ++j) ov[j] = (bf16)mv[d0 + j];
          *(bf16x4*)(outp + d0) = ov;
        }
    }
    __syncthreads();  // fence LDS reuse before next segment's STAGE
  }
#undef STAGE
#undef LDS_K
#undef LDS_V
}

// ---------------- launch ----------------
extern "C" void kernel_launch(void* const* d_in, const int* in_sizes, int n_in,
                              void* d_out, int out_size, void* d_ws, size_t ws_size,
                              hipStream_t stream) {
  const float* x = (const float*)d_in[0];
  const float* Wqkv = (const float*)d_in[1];
  const float* Wout = (const float*)d_in[2];
  const int* seq_lengths = (const int*)d_in[3];
  const int* wl = (const int*)d_in[4];
  const int* wr = (const int*)d_in[5];
  float* out = (float*)d_out;

  char* ws = (char*)d_ws;
  bf16* xb = (bf16*)ws;      ws += (size_t)8192 * 1024 * 2;
  bf16* wqkvb = (bf16*)ws;   ws += (size_t)3072 * 1024 * 2;
  bf16* woutb = (bf16*)ws;   ws += (size_t)1024 * 1024 * 2;
  bf16* qd = (bf16*)ws;      ws += (size_t)B_ * H_ * S_ * D_ * 2;
  bf16* kd = (bf16*)ws;      ws += (size_t)B_ * H_ * S_ * D_ * 2;
  bf16* vtd = (bf16*)ws;     ws += (size_t)B_ * H_ * S_ * D_ * 2;
  bf16* attn = (bf16*)ws;    ws += (size_t)8192 * 1024 * 2;
  float* meanv = (float*)ws; ws += (size_t)B_ * H_ * D_ * 4;

  cvt3_kernel<<<6144, 256, 0, stream>>>(x, xb, Wqkv, wqkvb, Wout, woutb);

  gemm_pipe<<<dim3(24, 32), 512, 0, stream>>>(xb, wqkvb, 8192, 3072, 1024, 0,
                                              qd, kd, vtd, nullptr);
  meanv_kernel<<<256, 256, 0, stream>>>(vtd, meanv);
  attn_kernel<<<512, 256, 0, stream>>>(qd, kd, vtd, meanv, seq_lengths, wl, wr,
                                       attn);
  gemm_pipe<<<dim3(8, 32), 512, 0, stream>>>(attn, woutb, 8192, 1024, 1024, 1,
                                             nullptr, nullptr, nullptr, out);
}

// Round 21
// 157.528 us; speedup vs baseline: 1.3999x; 1.0125x over previous
//
#include <hip/hip_runtime.h>

typedef __bf16 bf16;
typedef __attribute__((ext_vector_type(2))) __bf16 bf16x2;
typedef __attribute__((ext_vector_type(4))) __bf16 bf16x4;
typedef __attribute__((ext_vector_type(8))) __bf16 bf16x8;
typedef __attribute__((ext_vector_type(4))) float f32x4;
typedef __attribute__((ext_vector_type(16))) float f32x16;

#define B_ 4
#define S_ 2048
#define H_ 16
#define D_ 64
#define E_ 1024

#define BM 256
#define BN 128
#define BK 64

__device__ __forceinline__ int imin(int a, int b) { return a < b ? a : b; }
__device__ __forceinline__ int imax(int a, int b) { return a > b ? a : b; }

__device__ __forceinline__ void gload_lds16(const void* g, void* l) {
  __builtin_amdgcn_global_load_lds(
      (const __attribute__((address_space(1))) void*)g,
      (__attribute__((address_space(3))) void*)l, 16, 0, 0);
}

// ------ fused f32 -> bf16 convert for x (4096 blk), Wqkv (1536), Wout (512) --
__global__ __launch_bounds__(256) void cvt3_kernel(
    const float* __restrict__ x, bf16* __restrict__ xb,
    const float* __restrict__ wqkv, bf16* __restrict__ wqkvb,
    const float* __restrict__ wout, bf16* __restrict__ woutb) {
  const int bid = blockIdx.x;
  const float* in;
  bf16* out;
  int idx;
  if (bid < 4096) { in = x; out = xb; idx = bid; }
  else if (bid < 5632) { in = wqkv; out = wqkvb; idx = bid - 4096; }
  else { in = wout; out = woutb; idx = bid - 5632; }
  const int i = (idx * 256 + threadIdx.x) * 8;
  float4 v0 = *(const float4*)(in + i);
  float4 v1 = *(const float4*)(in + i + 4);
  bf16x8 o;
  o[0] = (bf16)v0.x; o[1] = (bf16)v0.y; o[2] = (bf16)v0.z; o[3] = (bf16)v0.w;
  o[4] = (bf16)v1.x; o[5] = (bf16)v1.y; o[6] = (bf16)v1.z; o[7] = (bf16)v1.w;
  *(bf16x8*)(out + i) = o;
}

// ------------- NT bf16 GEMM, 256x128 tile, 3-buf distance-2 pipeline -------
// Round-8 schedule (best measured). XCD mapping: QKV launch (gridDim.x==24)
// uses rectangular 8tm x 12tn regions per XCD, tn-inner, so the per-XCD B
// working set (12 x 256KB = 3MB) stays L2-resident (FETCH 86MB -> ~58MB
// predicted). Out-proj keeps the chunked mapping (B=2MB already L2-fits).
__global__ __launch_bounds__(512, 1) void gemm_pipe(
    const bf16* __restrict__ A, const bf16* __restrict__ Bm,
    int M, int N, int K, int mode,
    bf16* __restrict__ qd, bf16* __restrict__ kd, bf16* __restrict__ vtd,
    float* __restrict__ outf) {
  __shared__ __align__(16) bf16 As[3][BM * BK];
  __shared__ __align__(16) bf16 Bs[3][BN * BK];
  const int tid = threadIdx.x;
  const int wave = tid >> 6, lane = tid & 63;
  const int l15 = lane & 15, l4 = lane >> 4;
  const int wm = (wave >> 1) * 64;
  const int wn = (wave & 1) * 64;

  const int fid = blockIdx.y * gridDim.x + blockIdx.x;
  int tm, tn;
  if (gridDim.x == 24) {
    // QKV: 768 blocks, XCD x owns tm-group (x&3)*8..+7, tn-group (x>>2)*12..+11
    const int x = fid & 7;
    const int j = fid >> 3;  // 0..95
    tm = (x & 3) * 8 + (j / 12);
    tn = (x >> 2) * 12 + (j % 12);
  } else {
    const int nwg = gridDim.x * gridDim.y;
    const int chunk = nwg >> 3;
    const int swz = (fid & 7) * chunk + (fid >> 3);
    tn = swz % gridDim.x;
    tm = swz / gridDim.x;
  }

  const bf16* Abase = A + (size_t)tm * BM * K;
  const bf16* Bbase = Bm + (size_t)tn * BN * K;

  f32x4 acc[4][4];
#pragma unroll
  for (int i = 0; i < 4; ++i)
#pragma unroll
    for (int j = 0; j < 4; ++j)
#pragma unroll
      for (int r = 0; r < 4; ++r) acc[i][j][r] = 0.f;

  const int NT = K >> 6;

#define STAGE_A(sbuf, k0)                                                      \
  {                                                                            \
    _Pragma("unroll") for (int ld = 0; ld < 4; ++ld) {                         \
      const int idx = ld * 512 + tid;                                          \
      const int row = idx >> 3, g = idx & 7;                                   \
      const int gs = g ^ (row & 7);                                            \
      gload_lds16(Abase + (size_t)row * K + (k0) + gs * 8,                     \
                  As[sbuf] + (ld * 512 + wave * 64) * 8);                      \
    }                                                                          \
  }
#define STAGE_B(sbuf, k0)                                                      \
  {                                                                            \
    _Pragma("unroll") for (int ld = 0; ld < 2; ++ld) {                         \
      const int idx = ld * 512 + tid;                                          \
      const int row = idx >> 3, g = idx & 7;                                   \
      const int gs = g ^ (row & 7);                                            \
      gload_lds16(Bbase + (size_t)row * K + (k0) + gs * 8,                     \
                  Bs[sbuf] + (ld * 512 + wave * 64) * 8);                      \
    }                                                                          \
  }

  STAGE_A(0, 0); STAGE_B(0, 0);
  STAGE_A(1, BK); STAGE_B(1, BK);
  asm volatile("s_waitcnt vmcnt(6)" ::: "memory");
  __builtin_amdgcn_s_barrier();

  int p = 0;
  for (int t = 0; t < NT; ++t) {
    const bf16* Ap = As[p];
    const bf16* Bp = Bs[p];
    const int sb = (p + 2 >= 3) ? p - 1 : p + 2;
    const int sk0 = ((t + 2 < NT) ? t + 2 : NT - 1) * BK;

    bf16x8 a[4], bfr[4];
#pragma unroll
    for (int i = 0; i < 4; ++i) {
      const int ra = wm + i * 16 + l15;
      a[i] = *(const bf16x8*)(Ap + ra * 64 + ((l4 ^ (ra & 7)) * 8));
      const int rb = wn + i * 16 + l15;
      bfr[i] = *(const bf16x8*)(Bp + rb * 64 + ((l4 ^ (rb & 7)) * 8));
    }
    STAGE_A(sb, sk0);
    __builtin_amdgcn_s_setprio(1);
#pragma unroll
    for (int i = 0; i < 4; ++i)
#pragma unroll
      for (int j = 0; j < 4; ++j)
        acc[i][j] = __builtin_amdgcn_mfma_f32_16x16x32_bf16(a[i], bfr[j],
                                                            acc[i][j], 0, 0, 0);
    __builtin_amdgcn_s_setprio(0);
#pragma unroll
    for (int i = 0; i < 4; ++i) {
      const int ra = wm + i * 16 + l15;
      a[i] = *(const bf16x8*)(Ap + ra * 64 + (((4 + l4) ^ (ra & 7)) * 8));
      const int rb = wn + i * 16 + l15;
      bfr[i] = *(const bf16x8*)(Bp + rb * 64 + (((4 + l4) ^ (rb & 7)) * 8));
    }
    STAGE_B(sb, sk0);
    __builtin_amdgcn_s_setprio(1);
#pragma unroll
    for (int i = 0; i < 4; ++i)
#pragma unroll
      for (int j = 0; j < 4; ++j)
        acc[i][j] = __builtin_amdgcn_mfma_f32_16x16x32_bf16(a[i], bfr[j],
                                                            acc[i][j], 0, 0, 0);
    __builtin_amdgcn_s_setprio(0);

    asm volatile("s_waitcnt vmcnt(6)" ::: "memory");
    __builtin_amdgcn_s_barrier();
    p = (p + 1 >= 3) ? 0 : p + 1;
  }
#undef STAGE_A
#undef STAGE_B

  if (mode == 0) {
#pragma unroll
    for (int i = 0; i < 4; ++i) {
      const int m0 = tm * BM + wm + i * 16 + l4 * 4;
      const int b = m0 >> 11, s = m0 & (S_ - 1);
#pragma unroll
      for (int j = 0; j < 4; ++j) {
        const int n = tn * BN + wn + j * 16 + l15;
        const int which = n >> 10;
        const int hn = n & 1023;
        const int h = hn >> 6, d = hn & 63;
        const f32x4 av = acc[i][j];
        if (which == 0) {
#pragma unroll
          for (int r = 0; r < 4; ++r)
            qd[((size_t)(b * H_ + h) * S_ + (s + r)) * D_ + d] =
                (bf16)(av[r] * 0.125f);
        } else if (which == 1) {
#pragma unroll
          for (int r = 0; r < 4; ++r)
            kd[((size_t)(b * H_ + h) * S_ + (s + r)) * D_ + d] = (bf16)av[r];
        } else {
          bf16x4 pv;
#pragma unroll
          for (int r = 0; r < 4; ++r) pv[r] = (bf16)av[r];
          *(bf16x4*)(vtd + ((size_t)(b * H_ + h) * D_ + d) * S_ + s) = pv;
        }
      }
    }
  } else {
#pragma unroll
    for (int i = 0; i < 4; ++i) {
      const int m0 = tm * BM + wm + i * 16 + l4 * 4;
#pragma unroll
      for (int j = 0; j < 4; ++j) {
        const int n = tn * BN + wn + j * 16 + l15;
#pragma unroll
        for (int r = 0; r < 4; ++r) outf[(size_t)(m0 + r) * N + n] = acc[i][j][r];
      }
    }
  }
}

// ------- mean of v over all S: 256 blocks = 64 bh x 4 d-quarters ----------
__global__ __launch_bounds__(256) void meanv_kernel(const bf16* __restrict__ vt,
                                                    float* __restrict__ meanv) {
  const int bh = blockIdx.x >> 2, dq = blockIdx.x & 3;
  const int tid = threadIdx.x;
  const int dl = tid >> 4;
  const int sl = tid & 15;
  const int d = dq * 16 + dl;
  const bf16* row = vt + ((size_t)bh * D_ + d) * S_;
  float s = 0.f;
#pragma unroll
  for (int it = 0; it < 16; ++it) {
    bf16x8 v = *(const bf16x8*)(row + it * 128 + sl * 8);
#pragma unroll
    for (int j = 0; j < 8; ++j) s += (float)v[j];
  }
#pragma unroll
  for (int m = 1; m < 16; m <<= 1) s += __shfl_xor(s, m, 64);
  if (sl == 0) meanv[(size_t)bh * D_ + d] = s * (1.0f / (float)S_);
}

// -------- flash attention: pair blocks (g,15-g), KVBLK=128 staged ----------
__device__ __forceinline__ int pk2(float a, float b) {
  union { bf16x2 h; int i; } u;
  u.h[0] = (bf16)a; u.h[1] = (bf16)b;
  return u.i;
}

__global__ __launch_bounds__(256) void attn_kernel(
    const bf16* __restrict__ q, const bf16* __restrict__ k,
    const bf16* __restrict__ vt, const float* __restrict__ meanv,
    const int* __restrict__ seq_lengths, const int* __restrict__ wlp,
    const int* __restrict__ wrp, bf16* __restrict__ attn_out) {
  __shared__ __align__(16) bf16 Ks[2][128 * 64];
  __shared__ __align__(16) bf16 Vs[2][64 * 128];
  const int tid = threadIdx.x, wave = tid >> 6, lane = tid & 63;
  const int l31 = lane & 31, l5 = lane >> 5;
  const int bid0 = blockIdx.x;
  const int bid = (bid0 & 7) * 64 + (bid0 >> 3);
  const int bh = bid >> 3;
  const int gp = bid & 7;
  const int b = bh >> 4, h = bh & 15;
  const int seq_len = seq_lengths[b];
  const int wl = wlp[0], wr = wrp[0];

  const bf16* qbase = q + (size_t)bh * S_ * D_;
  const bf16* kbase = k + (size_t)bh * S_ * D_;
  const bf16* vtb = vt + (size_t)bh * D_ * S_;

#define STAGE(bufb, kt0)                                                       \
  {                                                                            \
    _Pragma("unroll") for (int ld = 0; ld < 4; ++ld) {                         \
      const int idx = ld * 256 + tid;                                          \
      const int krow_i = idx >> 3, kg_ = idx & 7;                              \
      const int kgs = kg_ ^ (krow_i & 7);                                      \
      const int krow = imin((kt0) + krow_i, S_ - 1);                           \
      gload_lds16(kbase + (size_t)krow * 64 + kgs * 8, Ks[bufb] + idx * 8);    \
      const int vrow = idx >> 4, vg_ = idx & 15;                               \
      const int vgs = vg_ ^ (vrow & 15);                                       \
      const int vcol = imin((kt0) + vgs * 8, S_ - 8);                          \
      gload_lds16(vtb + (size_t)vrow * S_ + vcol, Vs[bufb] + idx * 8);         \
    }                                                                          \
  }
#define LDS_K(bufb, row, gran)                                                 \
  (*(const bf16x8*)((const char*)(Ks[bufb]) + (row) * 128 +                    \
                    (((gran) ^ ((row) & 7)) << 4)))
#define LDS_V(bufb, row, gran)                                                 \
  (*(const bf16x8*)((const char*)(Vs[bufb]) + (row) * 256 +                    \
                    (((gran) ^ ((row) & 15)) << 4)))

  for (int seg = 0; seg < 2; ++seg) {
    const int g = seg ? (15 - gp) : gp;
    const int q0b = g * 128;
    const int q0w = q0b + wave * 32;

    bf16x8 qa[4];
#pragma unroll
    for (int dg = 0; dg < 4; ++dg)
      qa[dg] = *(const bf16x8*)(qbase + (size_t)(q0w + l31) * D_ +
                                dg * 16 + l5 * 8);

    const int hi_blk = (wr >= 0) ? imin(q0b + 127 + wr, S_ - 1) : (S_ - 1);
    const int end_blk = imin(hi_blk + 1, seq_len);
    const int lo_blk = (wl >= 0) ? imax(0, q0b - wl) : 0;
    const int beg_blk = lo_blk & ~127;
    const int ntb = (end_blk > beg_blk) ? ((end_blk - beg_blk + 127) >> 7) : 0;

    const int w_hi = (wr >= 0) ? (q0w + 31 + wr) : (S_ - 1);
    const int w_end = imin(w_hi + 1, seq_len);
    const int w_lo = (wl >= 0) ? imax(0, q0w - wl) : 0;

    f32x16 o0, o1;
#pragma unroll
    for (int r = 0; r < 16; ++r) { o0[r] = 0.f; o1[r] = 0.f; }
    float mrun = -1e30f, lrun = 0.f;

    if (ntb > 0) STAGE(0, beg_blk);
    __syncthreads();

    for (int t = 0; t < ntb; ++t) {
      const int kt = beg_blk + t * 128;
      if (t + 1 < ntb) STAGE((t + 1) & 1, kt + 128);
      const int bufb = t & 1;

#pragma unroll
      for (int kk = 0; kk < 2; ++kk) {
        const int kts = kt + kk * 64;
        const bool active = (kts < w_end) && (kts + 63 >= w_lo);
        if (active) {
          f32x16 sf0, sf1;
#pragma unroll
          for (int r = 0; r < 16; ++r) { sf0[r] = 0.f; sf1[r] = 0.f; }
#pragma unroll
          for (int dg = 0; dg < 4; ++dg) {
            bf16x8 kb0 = LDS_K(bufb, kk * 64 + l31, dg * 2 + l5);
            bf16x8 kb1 = LDS_K(bufb, kk * 64 + 32 + l31, dg * 2 + l5);
            sf0 = __builtin_amdgcn_mfma_f32_32x32x16_bf16(kb0, qa[dg], sf0,
                                                          0, 0, 0);
            sf1 = __builtin_amdgcn_mfma_f32_32x32x16_bf16(kb1, qa[dg], sf1,
                                                          0, 0, 0);
          }

          bool allv = (kts + 63 < seq_len);
          if (wr >= 0) allv = allv && (kts + 63 <= q0w + wr);
          if (wl >= 0) allv = allv && (kts >= q0w + 31 - wl);
          if (!allv) {
            const int qrow = q0w + l31;
#pragma unroll
            for (int hh = 0; hh < 2; ++hh)
#pragma unroll
              for (int r = 0; r < 16; ++r) {
                const int key = kts + hh * 32 + (r & 3) + 8 * (r >> 2) + 4 * l5;
                bool valid = (key < seq_len);
                if (wr >= 0) valid = valid && (key <= qrow + wr);
                if (wl >= 0) valid = valid && (key >= qrow - wl);
                if (hh == 0) sf0[r] = valid ? sf0[r] : -1e30f;
                else sf1[r] = valid ? sf1[r] : -1e30f;
              }
          }
          float tmax = -1e30f;
#pragma unroll
          for (int r = 0; r < 16; ++r) {
            tmax = fmaxf(tmax, sf0[r]);
            tmax = fmaxf(tmax, sf1[r]);
          }
          tmax = fmaxf(tmax, __shfl_xor(tmax, 32, 64));

          if (!__all(tmax <= mrun + 8.0f)) {
            const float mnew = fmaxf(mrun, tmax);
            const float corr = __expf(mrun - mnew);
            mrun = mnew;
            lrun *= corr;
#pragma unroll
            for (int r = 0; r < 16; ++r) { o0[r] *= corr; o1[r] *= corr; }
          }

          float lsum = 0.f;
#pragma unroll
          for (int r = 0; r < 16; ++r) {
            const float e0 = (sf0[r] <= -1e29f) ? 0.f : __expf(sf0[r] - mrun);
            const float e1 = (sf1[r] <= -1e29f) ? 0.f : __expf(sf1[r] - mrun);
            sf0[r] = e0; sf1[r] = e1;
            lsum += e0 + e1;
          }
          lsum += __shfl_xor(lsum, 32, 64);
          lrun += lsum;

          bf16x8 pb[4];
#pragma unroll
          for (int kg = 0; kg < 4; ++kg) {
            const int base = (kg & 1) * 8;
            float p0, p1, p2, p3, p4, p5, p6, p7;
            if (kg < 2) {
              p0 = sf0[base + 0]; p1 = sf0[base + 1]; p2 = sf0[base + 2];
              p3 = sf0[base + 3]; p4 = sf0[base + 4]; p5 = sf0[base + 5];
              p6 = sf0[base + 6]; p7 = sf0[base + 7];
            } else {
              p0 = sf1[base + 0]; p1 = sf1[base + 1]; p2 = sf1[base + 2];
              p3 = sf1[base + 3]; p4 = sf1[base + 4]; p5 = sf1[base + 5];
              p6 = sf1[base + 6]; p7 = sf1[base + 7];
            }
            const int w0 = pk2(p0, p1);
            const int w1 = pk2(p2, p3);
            const int w2 = pk2(p4, p5);
            const int w3 = pk2(p6, p7);
            auto r02 = __builtin_amdgcn_permlane32_swap(w0, w2, false, false);
            auto r13 = __builtin_amdgcn_permlane32_swap(w1, w3, false, false);
            union { int i[4]; bf16x8 v; } u;
            u.i[0] = r02[0]; u.i[1] = r13[0]; u.i[2] = r02[1]; u.i[3] = r13[1];
            pb[kg] = u.v;
          }

#pragma unroll
          for (int kg = 0; kg < 4; ++kg) {
            bf16x8 va0 = LDS_V(bufb, l31, kk * 8 + kg * 2 + l5);
            bf16x8 va1 = LDS_V(bufb, 32 + l31, kk * 8 + kg * 2 + l5);
            o0 = __builtin_amdgcn_mfma_f32_32x32x16_bf16(va0, pb[kg], o0,
                                                         0, 0, 0);
            o1 = __builtin_amdgcn_mfma_f32_32x32x16_bf16(va1, pb[kg], o1,
                                                         0, 0, 0);
          }
        }
      }
      __syncthreads();
    }

    // ---- epilogue for this segment ----
    const int qrow = q0w + l31;
    bf16* outp = attn_out + ((size_t)(b * S_ + qrow)) * E_ + h * 64;
    if (lrun > 0.f) {
      const float inv = 1.0f / lrun;
#pragma unroll
      for (int dg2 = 0; dg2 < 2; ++dg2) {
        const f32x16& o = dg2 ? o1 : o0;
#pragma unroll
        for (int rg = 0; rg < 4; ++rg) {
          const int d0 = dg2 * 32 + 8 * rg + 4 * l5;
          bf16x4 ov;
#pragma unroll
          for (int j = 0; j < 4; ++j) ov[j] = (bf16)(o[rg * 4 + j] * inv);
          *(bf16x4*)(outp + d0) = ov;
        }
      }
    } else {
      const float* mv = meanv + (size_t)bh * D_;
#pragma unroll
      for (int dg2 = 0; dg2 < 2; ++dg2)
#pragma unroll
        for (int rg = 0; rg < 4; ++rg) {
          const int d0 = dg2 * 32 + 8 * rg + 4 * l5;
          bf16x4 ov;
#pragma unroll
          for (int j = 0; j < 4; ++j) ov[j] = (bf16)mv[d0 + j];
          *(bf16x4*)(outp + d0) = ov;
        }
    }
    __syncthreads();  // fence LDS reuse before next segment's STAGE
  }
#undef STAGE
#undef LDS_K
#undef LDS_V
}

// ---------------- launch ----------------
extern "C" void kernel_launch(void* const* d_in, const int* in_sizes, int n_in,
                              void* d_out, int out_size, void* d_ws, size_t ws_size,
                              hipStream_t stream) {
  const float* x = (const float*)d_in[0];
  const float* Wqkv = (const float*)d_in[1];
  const float* Wout = (const float*)d_in[2];
  const int* seq_lengths = (const int*)d_in[3];
  const int* wl = (const int*)d_in[4];
  const int* wr = (const int*)d_in[5];
  float* out = (float*)d_out;

  char* ws = (char*)d_ws;
  bf16* xb = (bf16*)ws;      ws += (size_t)8192 * 1024 * 2;
  bf16* wqkvb = (bf16*)ws;   ws += (size_t)3072 * 1024 * 2;
  bf16* woutb = (bf16*)ws;   ws += (size_t)1024 * 1024 * 2;
  bf16* qd = (bf16*)ws;      ws += (size_t)B_ * H_ * S_ * D_ * 2;
  bf16* kd = (bf16*)ws;      ws += (size_t)B_ * H_ * S_ * D_ * 2;
  bf16* vtd = (bf16*)ws;     ws += (size_t)B_ * H_ * S_ * D_ * 2;
  bf16* attn = (bf16*)ws;    ws += (size_t)8192 * 1024 * 2;
  float* meanv = (float*)ws; ws += (size_t)B_ * H_ * D_ * 4;

  cvt3_kernel<<<6144, 256, 0, stream>>>(x, xb, Wqkv, wqkvb, Wout, woutb);

  gemm_pipe<<<dim3(24, 32), 512, 0, stream>>>(xb, wqkvb, 8192, 3072, 1024, 0,
                                              qd, kd, vtd, nullptr);
  meanv_kernel<<<256, 256, 0, stream>>>(vtd, meanv);
  attn_kernel<<<512, 256, 0, stream>>>(qd, kd, vtd, meanv, seq_lengths, wl, wr,
                                       attn);
  gemm_pipe<<<dim3(8, 32), 512, 0, stream>>>(attn, woutb, 8192, 1024, 1024, 1,
                                             nullptr, nullptr, nullptr, out);
}